// Round 10
// baseline (1038.988 us; speedup 1.0000x reference)
//
#include <hip/hip_runtime.h>
#include <hip/hip_bf16.h>
#include <math.h>

// Gen3Dmol_Classify: B=8 N=256 D=768 H=8 HD=96 F=3072 K=128 L=8 V=32 E=1024 C=2
// Round 10: R9 base; k_gauss 512-thr/128-pos + vectorized param reads;
// classifier merged back to one kernel.

#define DEV_INLINE __device__ __forceinline__

typedef __attribute__((ext_vector_type(8))) short short8v;
typedef __attribute__((ext_vector_type(4))) short short4v;
typedef __attribute__((ext_vector_type(4))) float f32x4;

DEV_INLINE unsigned short f2bf(float f) {          // RNE, manual
  unsigned u = __float_as_uint(f);
  return (unsigned short)((u + 0x7fffu + ((u >> 16) & 1u)) >> 16);
}
DEV_INLINE unsigned short f2bf_hw(float f) {
  __hip_bfloat16 h = __float2bfloat16(f);
  unsigned short u; __builtin_memcpy(&u, &h, 2); return u;
}
DEV_INLINE float bf2f(unsigned short u) {
  return __uint_as_float(((unsigned)u) << 16);
}
DEV_INLINE float gelu_f(float v) {                 // exact (residual-path users)
  return 0.5f * v * (1.0f + erff(v * 0.70710678118654752f));
}
DEV_INLINE float gelu_tanh(float x) {              // fast approx (gauss bias path)
  float x2 = x * x;
  float t  = x * fmaf(0.044715f, x2, 1.0f);
  float a  = fminf(2.3022082f * t, 252.0f);
  float e  = __builtin_amdgcn_exp2f(a);
  return x * e * __frcp_rn(e + 1.0f);
}
DEV_INLINE f32x4 zero4() { f32x4 z; z[0]=0.f; z[1]=0.f; z[2]=0.f; z[3]=0.f; return z; }

// ---------------------------------------------------------------------------
// Weight cast + transpose: W[K][N] fp32 -> Wt[N][K] bf16 (per blockIdx.z layer)
// ---------------------------------------------------------------------------
__global__ __launch_bounds__(256) void k_cast_t(
    const float* __restrict__ W, unsigned short* __restrict__ Wt, int K, int N)
{
  __shared__ float s[64][68];
  const int tid = threadIdx.x;
  const size_t lay = (size_t)blockIdx.z * K * N;
  const int k0 = blockIdx.x * 64, n0 = blockIdx.y * 64;
  const int r = tid >> 4, c4 = (tid & 15) << 2;
  #pragma unroll
  for (int i = 0; i < 4; ++i)
    *(float4*)&s[r + i * 16][c4] =
        *(const float4*)(W + lay + (size_t)(k0 + r + i * 16) * N + n0 + c4);
  __syncthreads();
  const int n = tid & 63, kc = (tid >> 6) << 4;
  short8v v0, v1;
  #pragma unroll
  for (int j = 0; j < 8; ++j) v0[j] = (short)f2bf(s[kc + j][n]);
  #pragma unroll
  for (int j = 0; j < 8; ++j) v1[j] = (short)f2bf(s[kc + 8 + j][n]);
  unsigned short* dst = Wt + lay + (size_t)(n0 + n) * K + k0 + kc;
  *(short8v*)dst = v0;
  *(short8v*)(dst + 8) = v1;
}

// gp1w cast with coef fold: g1t[n][k] = bf16(coef[k] * gp1w[k][n])
__global__ __launch_bounds__(128) void k_cast_g1(
    const float* __restrict__ gp1w, const float* __restrict__ gstds,
    unsigned short* __restrict__ g1t)
{
  const int k = threadIdx.x;
  const int n = blockIdx.x;
  float sd = fabsf(gstds[k]) + 1e-5f;
  float coef = 0.39894268f / sd;
  g1t[n * 128 + k] = f2bf(coef * gp1w[k * 128 + n]);
}

// ---------------------------------------------------------------------------
// MFMA GEMM (R1/R6-proven reg-staged, 2 barriers/K-tile), templated tile.
// C[2048][N] = A[2048][K](bf16) @ Bt[N][K]^T + bias
// EPI: 0 bias->bf16 | 1 bias+gelu->bf16 | 2 bias+res->fp32 | 4 bias->bf16 P+Vt
// ---------------------------------------------------------------------------
template<int BM, int BN, int EPI>
__global__ __launch_bounds__(256) void k_gemm(
    const unsigned short* __restrict__ A, const unsigned short* __restrict__ Bt,
    const float* __restrict__ bias, const float* __restrict__ res,
    void* __restrict__ C, unsigned short* __restrict__ Vt, int N, int K)
{
  constexpr int MA = BM / 32;
  constexpr int NB = BN / 32;
  __shared__ __align__(16) unsigned short As[BM * 64];
  __shared__ __align__(16) unsigned short Bs[BN * 64];
  const int tid = threadIdx.x;
  const int l = tid & 63;
  const int w = tid >> 6, wr = w >> 1, wc = w & 1;
  const int row0 = blockIdx.x * BM, col0 = blockIdx.y * BN;
  const int NT = K >> 6;

  const int rA = tid >> 3;
  const int cs = (((tid & 7) * 16) ^ ((rA & 7) << 4)) >> 1;
  const unsigned short* pa = A + (size_t)(row0 + rA) * K + (tid & 7) * 8;
  const unsigned short* pb = Bt + (size_t)(col0 + rA) * K + (tid & 7) * 8;

  short8v ra[MA], rb[NB];
  #pragma unroll
  for (int i = 0; i < MA; ++i) ra[i] = *(const short8v*)(pa + (size_t)i * 32 * K);
  #pragma unroll
  for (int i = 0; i < NB; ++i) rb[i] = *(const short8v*)(pb + (size_t)i * 32 * K);

  f32x4 acc[MA][NB];
  #pragma unroll
  for (int mi = 0; mi < MA; ++mi)
    #pragma unroll
    for (int ni = 0; ni < NB; ++ni) acc[mi][ni] = zero4();

  for (int kt = 0; kt < NT; ++kt) {
    #pragma unroll
    for (int i = 0; i < MA; ++i) *(short8v*)&As[(rA + i * 32) * 64 + cs] = ra[i];
    #pragma unroll
    for (int i = 0; i < NB; ++i) *(short8v*)&Bs[(rA + i * 32) * 64 + cs] = rb[i];
    __syncthreads();
    if (kt + 1 < NT) {
      const unsigned short* qa = pa + (size_t)(kt + 1) * 64;
      const unsigned short* qb = pb + (size_t)(kt + 1) * 64;
      #pragma unroll
      for (int i = 0; i < MA; ++i) ra[i] = *(const short8v*)(qa + (size_t)i * 32 * K);
      #pragma unroll
      for (int i = 0; i < NB; ++i) rb[i] = *(const short8v*)(qb + (size_t)i * 32 * K);
    }
    #pragma unroll
    for (int kk = 0; kk < 2; ++kk) {
      short8v af[MA], bf_[NB];
      #pragma unroll
      for (int mi = 0; mi < MA; ++mi) {
        int rw = wr * (BM / 2) + mi * 16 + (l & 15);
        int kb = (kk * 64 + ((l >> 4) << 4)) ^ ((rw & 7) << 4);
        af[mi] = *(const short8v*)&As[rw * 64 + (kb >> 1)];
      }
      #pragma unroll
      for (int ni = 0; ni < NB; ++ni) {
        int rw = wc * (BN / 2) + ni * 16 + (l & 15);
        int kb = (kk * 64 + ((l >> 4) << 4)) ^ ((rw & 7) << 4);
        bf_[ni] = *(const short8v*)&Bs[rw * 64 + (kb >> 1)];
      }
      #pragma unroll
      for (int mi = 0; mi < MA; ++mi)
        #pragma unroll
        for (int ni = 0; ni < NB; ++ni)
          acc[mi][ni] = __builtin_amdgcn_mfma_f32_16x16x32_bf16(
              af[mi], bf_[ni], acc[mi][ni], 0, 0, 0);
    }
    __syncthreads();
  }

  const int cl = l & 15, rg = (l >> 4) << 2;
  #pragma unroll
  for (int mi = 0; mi < MA; ++mi) {
    #pragma unroll
    for (int ni = 0; ni < NB; ++ni) {
      const int colg = col0 + wc * (BN / 2) + ni * 16 + cl;
      const float bv = bias[colg];
      const size_t rbase = (size_t)(row0 + wr * (BM / 2) + mi * 16 + rg);
      if (EPI == 4) {
        short4v pk;
        #pragma unroll
        for (int r = 0; r < 4; ++r) {
          float v = acc[mi][ni][r] + bv;
          unsigned short bb = f2bf(v);
          ((unsigned short*)C)[(rbase + r) * N + colg] = bb;
          pk[r] = (short)bb;
        }
        const int hh = colg / 96, dd = colg - hh * 96;
        const int bb_ = (int)(rbase >> 8), tok = (int)(rbase & 255);
        *(short4v*)(Vt + ((size_t)((bb_ << 3) + hh) * 96 + dd) * 256 + tok) = pk;
      } else {
        #pragma unroll
        for (int r = 0; r < 4; ++r) {
          size_t off = (rbase + r) * N + colg;
          float v = acc[mi][ni][r] + bv;
          if (EPI == 0) ((unsigned short*)C)[off] = f2bf(v);
          if (EPI == 1) ((unsigned short*)C)[off] = f2bf(gelu_f(v));
          if (EPI == 2) ((float*)C)[off] = v + res[off];
        }
      }
    }
  }
}

// ---------------------------------------------------------------------------
// Gaussian edge features + MLP via MFMA. 512 thr = 8 waves, 128 pos/block
// (grid 4096): setup amortized 2x, ~32 waves/CU theoretical. Params packed
// (mean,c2) float2 -> float4 vector LDS reads (broadcast, conflict-free).
// ---------------------------------------------------------------------------
__global__ __launch_bounds__(512) void k_gauss(
    const float* __restrict__ dist, const int* __restrict__ edge,
    const float* __restrict__ gmul, const float* __restrict__ gbias,
    const float* __restrict__ gmeans, const float* __restrict__ gstds,
    const unsigned short* __restrict__ gp1wt, const float* __restrict__ gp1b,
    const float* __restrict__ gp2w, const float* __restrict__ gp2b,
    unsigned short* __restrict__ bias_out)
{
  __shared__ __align__(16) float2 mc[128];   // (mean, c2)
  __shared__ float b1s[128];
  __shared__ float b2s[8];
  __shared__ __align__(16) unsigned short w2t[16 * 136];
  __shared__ __align__(16) unsigned short t1[8][2048];  // per-wave 16x128 bf16
  const int tid = threadIdx.x, l = tid & 63, w = tid >> 6;  // w: 0..7
  const int pos0 = blockIdx.x * 128;

  if (tid < 128) {
    float sd = fabsf(gstds[tid]) + 1e-5f;
    float inv = 1.0f / sd;
    mc[tid] = make_float2(gmeans[tid], -0.72134752f * inv * inv);  // -log2e/2*inv^2
    b1s[tid] = gp1b[tid];
  }
  if (tid < 8) b2s[tid] = gp2b[tid];
  for (int i = tid; i < 2048; i += 512) {
    int hh = i & 15, k = i >> 4;
    w2t[hh * 136 + k] = (hh < 8) ? f2bf(gp2w[k * 8 + hh]) : (unsigned short)0;
  }
  __syncthreads();   // the only barrier

  const int p = pos0 + w * 16 + (l & 15);
  const int et = edge[p];
  const float y = gmul[et] * dist[p] + gbias[et];

  // phase A: gaussians straight into A-fragments; params via float4 reads
  short8v ga[4];
  #pragma unroll
  for (int ks = 0; ks < 4; ++ks) {
    const int k0 = ks * 32 + ((l >> 4) << 3);
    const float4 q0 = *(const float4*)&mc[k0];       // mean0,c20,mean1,c21
    const float4 q1 = *(const float4*)&mc[k0 + 2];
    const float4 q2 = *(const float4*)&mc[k0 + 4];
    const float4 q3 = *(const float4*)&mc[k0 + 6];
    float d;
    d = y - q0.x; ga[ks][0] = (short)f2bf_hw(__builtin_amdgcn_exp2f(q0.y * d * d));
    d = y - q0.z; ga[ks][1] = (short)f2bf_hw(__builtin_amdgcn_exp2f(q0.w * d * d));
    d = y - q1.x; ga[ks][2] = (short)f2bf_hw(__builtin_amdgcn_exp2f(q1.y * d * d));
    d = y - q1.z; ga[ks][3] = (short)f2bf_hw(__builtin_amdgcn_exp2f(q1.w * d * d));
    d = y - q2.x; ga[ks][4] = (short)f2bf_hw(__builtin_amdgcn_exp2f(q2.y * d * d));
    d = y - q2.z; ga[ks][5] = (short)f2bf_hw(__builtin_amdgcn_exp2f(q2.w * d * d));
    d = y - q3.x; ga[ks][6] = (short)f2bf_hw(__builtin_amdgcn_exp2f(q3.y * d * d));
    d = y - q3.z; ga[ks][7] = (short)f2bf_hw(__builtin_amdgcn_exp2f(q3.w * d * d));
  }
  // phase B: t = g @ (coef-folded W1), B-frags from L2-hot g1t
  f32x4 acc[8];
  #pragma unroll
  for (int n = 0; n < 8; ++n) {
    acc[n] = zero4();
    const unsigned short* bp = gp1wt + (size_t)(n * 16 + (l & 15)) * 128 + ((l >> 4) << 3);
    #pragma unroll
    for (int ks = 0; ks < 4; ++ks)
      acc[n] = __builtin_amdgcn_mfma_f32_16x16x32_bf16(
          ga[ks], *(const short8v*)(bp + ks * 32), acc[n], 0, 0, 0);
  }
  // tanh-gelu -> per-wave t1 (windowed swizzle)
  unsigned short* tw = t1[w];
  {
    const int rb = (l >> 4) << 2;
    #pragma unroll
    for (int n = 0; n < 8; ++n) {
      int col2 = (n * 16 + (l & 15)) * 2;
      float bb = b1s[n * 16 + (l & 15)];
      #pragma unroll
      for (int r = 0; r < 4; ++r) {
        int row = rb + r;
        int swz = ((row & 3) << 4) ^ ((row >> 2) << 5);
        tw[(row * 256 + (col2 ^ swz)) >> 1] = f2bf_hw(gelu_tanh(acc[n][r] + bb));
      }
    }
  }
  // phase C: pb = t1 @ gp2w (same-wave LDS dep, no barrier)
  f32x4 o4 = zero4();
  {
    const int row = l & 15;
    const int swz = ((row & 3) << 4) ^ ((row >> 2) << 5);
    #pragma unroll
    for (int ks = 0; ks < 4; ++ks) {
      short8v af = *(const short8v*)&tw[(row * 256 + ((ks * 64 + ((l >> 4) << 4)) ^ swz)) >> 1];
      short8v bf_ = *(const short8v*)&w2t[(l & 15) * 136 + ks * 32 + ((l >> 4) << 3)];
      o4 = __builtin_amdgcn_mfma_f32_16x16x32_bf16(af, bf_, o4, 0, 0, 0);
    }
  }
  const int hh = l & 15;
  if (hh < 8) {
    int b = pos0 >> 16;
    int ij = (pos0 & 65535) + w * 16 + ((l >> 4) << 2);
    short4v ov;
    #pragma unroll
    for (int r = 0; r < 4; ++r) ov[r] = (short)f2bf(o4[r] + b2s[hh]);
    *(short4v*)(bias_out + (((size_t)((b << 3) + hh)) << 16) + ij) = ov;
  }
}

// ---------------------------------------------------------------------------
// Embedding gather + LN_emb -> x, then LN1 -> hO bf16 (fused, one kernel)
// ---------------------------------------------------------------------------
__global__ __launch_bounds__(256) void k_embed2(
    const float* __restrict__ emb, const int* __restrict__ tokens,
    const float* __restrict__ eg, const float* __restrict__ eb,
    const float* __restrict__ g1, const float* __restrict__ bp1,
    float* __restrict__ x, unsigned short* __restrict__ h)
{
  __shared__ float red[4], red2[4];
  const int t = threadIdx.x;
  const int row = blockIdx.x;
  const float* xr = emb + (size_t)tokens[row] * 768;
  float v0 = xr[t], v1 = xr[t + 256], v2 = xr[t + 512];
  float s = v0 + v1 + v2;
  #pragma unroll
  for (int o = 32; o; o >>= 1) s += __shfl_down(s, o);
  if ((t & 63) == 0) red[t >> 6] = s;
  __syncthreads();
  float mean = (red[0] + red[1] + red[2] + red[3]) * (1.0f / 768.0f);
  float d0 = v0 - mean, d1 = v1 - mean, d2 = v2 - mean;
  float q = d0 * d0 + d1 * d1 + d2 * d2;
  #pragma unroll
  for (int o = 32; o; o >>= 1) q += __shfl_down(q, o);
  if ((t & 63) == 0) red2[t >> 6] = q;
  __syncthreads();
  float rstd = rsqrtf((red2[0] + red2[1] + red2[2] + red2[3]) * (1.0f / 768.0f) + 1e-3f);
  float* outr = x + (size_t)row * 768;
  float y0 = d0 * rstd * eg[t]       + eb[t];
  float y1 = d1 * rstd * eg[t + 256] + eb[t + 256];
  float y2 = d2 * rstd * eg[t + 512] + eb[t + 512];
  outr[t] = y0; outr[t + 256] = y1; outr[t + 512] = y2;
  __syncthreads();
  s = y0 + y1 + y2;
  #pragma unroll
  for (int o = 32; o; o >>= 1) s += __shfl_down(s, o);
  if ((t & 63) == 0) red[t >> 6] = s;
  __syncthreads();
  mean = (red[0] + red[1] + red[2] + red[3]) * (1.0f / 768.0f);
  d0 = y0 - mean; d1 = y1 - mean; d2 = y2 - mean;
  q = d0 * d0 + d1 * d1 + d2 * d2;
  #pragma unroll
  for (int o = 32; o; o >>= 1) q += __shfl_down(q, o);
  if ((t & 63) == 0) red2[t >> 6] = q;
  __syncthreads();
  rstd = rsqrtf((red2[0] + red2[1] + red2[2] + red2[3]) * (1.0f / 768.0f) + 1e-3f);
  unsigned short* hr = h + (size_t)row * 768;
  hr[t]       = f2bf(d0 * rstd * g1[t]       + bp1[t]);
  hr[t + 256] = f2bf(d1 * rstd * g1[t + 256] + bp1[t + 256]);
  hr[t + 512] = f2bf(d2 * rstd * g1[t + 512] + bp1[t + 512]);
}

// LayerNorm fp32 -> bf16 h
__global__ __launch_bounds__(256) void k_ln_bf(
    const float* __restrict__ in, const float* __restrict__ g,
    const float* __restrict__ bp, unsigned short* __restrict__ out)
{
  __shared__ float red[4], red2[4];
  const int t = threadIdx.x;
  const size_t base = (size_t)blockIdx.x * 768;
  const float* xr = in + base;
  float v0 = xr[t], v1 = xr[t + 256], v2 = xr[t + 512];
  float s = v0 + v1 + v2;
  #pragma unroll
  for (int o = 32; o; o >>= 1) s += __shfl_down(s, o);
  if ((t & 63) == 0) red[t >> 6] = s;
  __syncthreads();
  float mean = (red[0] + red[1] + red[2] + red[3]) * (1.0f / 768.0f);
  float d0 = v0 - mean, d1 = v1 - mean, d2 = v2 - mean;
  float q = d0 * d0 + d1 * d1 + d2 * d2;
  #pragma unroll
  for (int o = 32; o; o >>= 1) q += __shfl_down(q, o);
  if ((t & 63) == 0) red2[t >> 6] = q;
  __syncthreads();
  float rstd = rsqrtf((red2[0] + red2[1] + red2[2] + red2[3]) * (1.0f / 768.0f) + 1e-3f);
  unsigned short* outr = out + base;
  outr[t]       = f2bf(d0 * rstd * g[t]       + bp[t]);
  outr[t + 256] = f2bf(d1 * rstd * g[t + 256] + bp[t + 256]);
  outr[t + 512] = f2bf(d2 * rstd * g[t + 512] + bp[t + 512]);
}

// ---------------------------------------------------------------------------
// Fused attention: probs = softmax(scale*Q.K^T + bias_bf16); O = probs @ V.
// 256 thr = 4 waves x 16 q-rows; K/V frags from L2-hot global; zero barriers.
// V-block n=0 prefetched before softmax.
// ---------------------------------------------------------------------------
__global__ __launch_bounds__(256) void k_attn(
    const unsigned short* __restrict__ P, const unsigned short* __restrict__ Vt,
    const unsigned short* __restrict__ bias, unsigned short* __restrict__ O)
{
  __shared__ __align__(16) unsigned short pl[4][4096];
  const int tid = threadIdx.x, l = tid & 63, w = tid >> 6;
  const int i0 = blockIdx.x << 6, bh = blockIdx.y, b = bh >> 3, hh = bh & 7;
  const unsigned short* Pb = P + (size_t)b * 196608 + hh * 96;

  short8v aq[3];
  const int rq = i0 + w * 16 + (l & 15);
  #pragma unroll
  for (int ks = 0; ks < 3; ++ks)
    aq[ks] = *(const short8v*)(Pb + (size_t)rq * 768 + ks * 32 + ((l >> 4) << 3));

  f32x4 acc[16];
  __builtin_amdgcn_s_setprio(1);
  #pragma unroll
  for (int n = 0; n < 16; ++n) {
    acc[n] = zero4();
    const unsigned short* kp = Pb + (size_t)(n * 16 + (l & 15)) * 768 + ((l >> 4) << 3);
    #pragma unroll
    for (int ks = 0; ks < 3; ++ks)
      acc[n] = __builtin_amdgcn_mfma_f32_16x16x32_bf16(
          aq[ks], *(const short8v*)(kp + ks * 32), acc[n], 0, 0, 0);
  }
  __builtin_amdgcn_s_setprio(0);

  // prefetch V fragments for PV n=0 (independent of softmax)
  short8v vb0[8];
  {
    const unsigned short* vbp = Vt + ((size_t)bh * 96 + (l & 15)) * 256 + ((l >> 4) << 3);
    #pragma unroll
    for (int ks = 0; ks < 8; ++ks) vb0[ks] = *(const short8v*)(vbp + ks * 32);
  }

  const float scale = 0.10206207261596577f;  // 1/sqrt(96)
  float inv[4];
  unsigned short* plw = pl[w];
  const size_t brow = ((size_t)bh * 256 + i0 + w * 16 + ((l >> 4) << 2)) * 256 + (l & 15);
  #pragma unroll
  for (int r = 0; r < 4; ++r) {
    const unsigned short* bptr = bias + brow + (size_t)r * 256;
    float m = -1e30f;
    #pragma unroll
    for (int n = 0; n < 16; ++n) {
      float v = fmaf(acc[n][r], scale, bf2f(bptr[n * 16]));
      acc[n][r] = v;
      m = fmaxf(m, v);
    }
    m = fmaxf(m, __shfl_xor(m, 1)); m = fmaxf(m, __shfl_xor(m, 2));
    m = fmaxf(m, __shfl_xor(m, 4)); m = fmaxf(m, __shfl_xor(m, 8));
    const int rowL = ((l >> 4) << 2) + r;
    const int swz = ((rowL & 3) << 4) ^ ((rowL >> 2) << 5);
    const int cb = (l & 15) << 1;
    float s = 0.f;
    #pragma unroll
    for (int n = 0; n < 16; ++n) {
      float e = __expf(acc[n][r] - m);
      s += e;
      plw[(rowL * 512 + ((cb + (n << 5)) ^ swz)) >> 1] = f2bf_hw(e);
    }
    s += __shfl_xor(s, 1); s += __shfl_xor(s, 2);
    s += __shfl_xor(s, 4); s += __shfl_xor(s, 8);
    inv[r] = 1.0f / s;
  }

  const int rowA = l & 15;
  const int swzA = ((rowA & 3) << 4) ^ ((rowA >> 2) << 5);
  short8v pa[8];
  #pragma unroll
  for (int ks = 0; ks < 8; ++ks)
    pa[ks] = *(const short8v*)&plw[(rowA * 512 + ((ks * 64 + ((l >> 4) << 4)) ^ swzA)) >> 1];

  unsigned short* Ob = O + ((size_t)b * 256 + i0 + w * 16 + ((l >> 4) << 2)) * 768
                       + hh * 96 + (l & 15);
  __builtin_amdgcn_s_setprio(1);
  #pragma unroll
  for (int n = 0; n < 6; ++n) {
    f32x4 a2 = zero4();
    const unsigned short* vb = Vt + ((size_t)bh * 96 + n * 16 + (l & 15)) * 256 + ((l >> 4) << 3);
    #pragma unroll
    for (int ks = 0; ks < 8; ++ks) {
      short8v bv = (n == 0) ? vb0[ks] : *(const short8v*)(vb + ks * 32);
      a2 = __builtin_amdgcn_mfma_f32_16x16x32_bf16(pa[ks], bv, a2, 0, 0, 0);
    }
    #pragma unroll
    for (int r = 0; r < 4; ++r)
      Ob[(size_t)r * 768 + n * 16] = f2bf(a2[r] * inv[r]);
  }
  __builtin_amdgcn_s_setprio(0);
}

// ---------------------------------------------------------------------------
// Final LN (row 0 of each batch) + classifier head -> out (8,2), one kernel
// ---------------------------------------------------------------------------
__global__ __launch_bounds__(256) void k_cls(
    const float* __restrict__ x, const float* __restrict__ fg,
    const float* __restrict__ fb, const float* __restrict__ w1,
    const float* __restrict__ b1, const float* __restrict__ w2,
    const float* __restrict__ b2, float* __restrict__ out)
{
  __shared__ float ln[768];
  __shared__ float t1[768];
  __shared__ float red[8];
  __shared__ float r2[8];
  const int t = threadIdx.x;
  const int b = blockIdx.x;
  const float* xr = x + (size_t)b * 196608;
  float v0 = xr[t], v1 = xr[t + 256], v2 = xr[t + 512];
  float s = v0 + v1 + v2;
  #pragma unroll
  for (int o = 32; o; o >>= 1) s += __shfl_down(s, o);
  if ((t & 63) == 0) red[t >> 6] = s;
  __syncthreads();
  float mean = (red[0] + red[1] + red[2] + red[3]) * (1.0f / 768.0f);
  float d0 = v0 - mean, d1 = v1 - mean, d2 = v2 - mean;
  float q = d0 * d0 + d1 * d1 + d2 * d2;
  #pragma unroll
  for (int o = 32; o; o >>= 1) q += __shfl_down(q, o);
  if ((t & 63) == 0) red[4 + (t >> 6)] = q;
  __syncthreads();
  float rstd = rsqrtf((red[4] + red[5] + red[6] + red[7]) * (1.0f / 768.0f) + 1e-3f);
  ln[t]       = d0 * rstd * fg[t]       + fb[t];
  ln[t + 256] = d1 * rstd * fg[t + 256] + fb[t + 256];
  ln[t + 512] = d2 * rstd * fg[t + 512] + fb[t + 512];
  __syncthreads();
  float a0 = b1[t], a1 = b1[t + 256], a2 = b1[t + 512];
  for (int d = 0; d < 768; ++d) {
    float lv = ln[d];
    a0 = fmaf(lv, w1[d * 768 + t], a0);
    a1 = fmaf(lv, w1[d * 768 + t + 256], a1);
    a2 = fmaf(lv, w1[d * 768 + t + 512], a2);
  }
  t1[t]       = gelu_f(a0);
  t1[t + 256] = gelu_f(a1);
  t1[t + 512] = gelu_f(a2);
  __syncthreads();
  float p0 = 0.f, p1 = 0.f;
  #pragma unroll
  for (int oo = 0; oo < 3; ++oo) {
    int d = t + oo * 256;
    p0 = fmaf(t1[d], w2[d * 2], p0);
    p1 = fmaf(t1[d], w2[d * 2 + 1], p1);
  }
  #pragma unroll
  for (int o = 32; o; o >>= 1) {
    p0 += __shfl_down(p0, o);
    p1 += __shfl_down(p1, o);
  }
  if ((t & 63) == 0) { r2[t >> 6] = p0; r2[4 + (t >> 6)] = p1; }
  __syncthreads();
  if (t == 0) {
    out[b * 2]     = r2[0] + r2[1] + r2[2] + r2[3] + b2[0];
    out[b * 2 + 1] = r2[4] + r2[5] + r2[6] + r2[7] + b2[1];
  }
}

// ---------------------------------------------------------------------------
extern "C" void kernel_launch(void* const* d_in, const int* in_sizes, int n_in,
                              void* d_out, int out_size, void* d_ws, size_t ws_size,
                              hipStream_t stream)
{
  const float* dist    = (const float*)d_in[0];
  const float* tok_emb = (const float*)d_in[1];
  const float* gmeans  = (const float*)d_in[2];
  const float* gstds   = (const float*)d_in[3];
  const float* gmul    = (const float*)d_in[4];
  const float* gbias   = (const float*)d_in[5];
  const float* gp1w    = (const float*)d_in[6];
  const float* gp1b    = (const float*)d_in[7];
  const float* gp2w    = (const float*)d_in[8];
  const float* gp2b    = (const float*)d_in[9];
  const float* embg    = (const float*)d_in[10];
  const float* embb    = (const float*)d_in[11];
  const float* Wq      = (const float*)d_in[12];
  const float* bq      = (const float*)d_in[13];
  const float* Wo      = (const float*)d_in[14];
  const float* bo      = (const float*)d_in[15];
  const float* ln1g    = (const float*)d_in[16];
  const float* ln1b    = (const float*)d_in[17];
  const float* W1      = (const float*)d_in[18];
  const float* b1      = (const float*)d_in[19];
  const float* W2      = (const float*)d_in[20];
  const float* b2      = (const float*)d_in[21];
  const float* ln2g    = (const float*)d_in[22];
  const float* ln2b    = (const float*)d_in[23];
  const float* fing    = (const float*)d_in[24];
  const float* finb    = (const float*)d_in[25];
  const float* cw1     = (const float*)d_in[26];
  const float* cb1     = (const float*)d_in[27];
  const float* cw2     = (const float*)d_in[28];
  const float* cb2     = (const float*)d_in[29];
  const int*   tokens  = (const int*)d_in[30];
  const int*   edge    = (const int*)d_in[31];

  // workspace layout
  float* ws   = (float*)d_ws;
  float* x    = ws;                        // 1,572,864 f32
  unsigned short* biasb = (unsigned short*)(x + 1572864); // 4,194,304 bf16
  unsigned short* hO  = biasb + 4194304;                  // 1,572,864 bf16 (h & O)
  unsigned short* P   = hO + 1572864;                     // 1,572,864 bf16
  unsigned short* Vt  = P + 1572864;                      // 1,572,864 bf16
  unsigned short* f1  = Vt + 1572864;                     // 6,291,456 bf16
  unsigned short* Wqt = f1 + 6291456;                     // 4,718,592 bf16
  unsigned short* Wot = Wqt + 4718592;                    // 4,718,592 bf16
  unsigned short* W1t = Wot + 4718592;                    // 18,874,368 bf16
  unsigned short* W2t = W1t + 18874368;                   // 18,874,368 bf16
  unsigned short* g1t = W2t + 18874368;                   // 16,384 bf16
  // total ~131 MiB

  k_cast_g1<<<128, 128, 0, stream>>>(gp1w, gstds, g1t);
  k_gauss<<<4096, 512, 0, stream>>>(dist, edge, gmul, gbias, gmeans, gstds,
                                    g1t, gp1b, gp2w, gp2b, biasb);
  k_cast_t<<<dim3(12, 12, 8), 256, 0, stream>>>(Wq, Wqt, 768, 768);
  k_cast_t<<<dim3(12, 12, 8), 256, 0, stream>>>(Wo, Wot, 768, 768);
  k_cast_t<<<dim3(12, 48, 8), 256, 0, stream>>>(W1, W1t, 768, 3072);
  k_cast_t<<<dim3(48, 12, 8), 256, 0, stream>>>(W2, W2t, 3072, 768);
  k_embed2<<<2048, 256, 0, stream>>>(tok_emb, tokens, embg, embb, ln1g, ln1b, x, hO);

  for (int l = 0; l < 8; ++l) {
    // QKV: epilogue writes P (bf16) and Vt (transposed)
    k_gemm<64, 64, 4><<<dim3(32, 12), 256, 0, stream>>>(
        hO, Wqt + (size_t)l * 589824, bq + l * 768, nullptr, P, Vt, 768, 768);
    k_attn<<<dim3(4, 64), 256, 0, stream>>>(P, Vt, biasb, hO);
    // Wo: x += Wo(O)+bo
    k_gemm<64, 64, 2><<<dim3(32, 12), 256, 0, stream>>>(
        hO, Wot + (size_t)l * 589824, bo + l * 768, x, x, nullptr, 768, 768);
    k_ln_bf<<<2048, 256, 0, stream>>>(x, ln2g + l * 768, ln2b + l * 768, hO);
    // FFN1: gelu -> f1 (bf16)
    k_gemm<128, 128, 1><<<dim3(16, 24), 256, 0, stream>>>(
        hO, W1t + (size_t)l * 2359296, b1 + l * 3072, nullptr, f1, nullptr, 3072, 768);
    // FFN2: x += FFN2(f1)+b2
    k_gemm<64, 64, 2><<<dim3(32, 12), 256, 0, stream>>>(
        f1, W2t + (size_t)l * 2359296, b2 + l * 768, x, x, nullptr, 768, 3072);
    if (l < 7)
      k_ln_bf<<<2048, 256, 0, stream>>>(x, ln1g + (l + 1) * 768,
                                        ln1b + (l + 1) * 768, hO);
  }
  k_cls<<<8, 256, 0, stream>>>(x, fing, finb, cw1, cb1, cw2, cb2, (float*)d_out);
}

// Round 11
// 1015.616 us; speedup vs baseline: 1.0230x; 1.0230x over previous
//
#include <hip/hip_runtime.h>
#include <hip/hip_bf16.h>
#include <math.h>

// Gen3Dmol_Classify: B=8 N=256 D=768 H=8 HD=96 F=3072 K=128 L=8 V=32 E=1024 C=2
// Round 11: R10 base; classifier re-split (R9-proven); attn 128-thr/512 blocks.

#define DEV_INLINE __device__ __forceinline__

typedef __attribute__((ext_vector_type(8))) short short8v;
typedef __attribute__((ext_vector_type(4))) short short4v;
typedef __attribute__((ext_vector_type(4))) float f32x4;

DEV_INLINE unsigned short f2bf(float f) {          // RNE, manual
  unsigned u = __float_as_uint(f);
  return (unsigned short)((u + 0x7fffu + ((u >> 16) & 1u)) >> 16);
}
DEV_INLINE unsigned short f2bf_hw(float f) {
  __hip_bfloat16 h = __float2bfloat16(f);
  unsigned short u; __builtin_memcpy(&u, &h, 2); return u;
}
DEV_INLINE float bf2f(unsigned short u) {
  return __uint_as_float(((unsigned)u) << 16);
}
DEV_INLINE float gelu_f(float v) {                 // exact (residual-path users)
  return 0.5f * v * (1.0f + erff(v * 0.70710678118654752f));
}
DEV_INLINE float gelu_tanh(float x) {              // fast approx (gauss bias path)
  float x2 = x * x;
  float t  = x * fmaf(0.044715f, x2, 1.0f);
  float a  = fminf(2.3022082f * t, 252.0f);
  float e  = __builtin_amdgcn_exp2f(a);
  return x * e * __frcp_rn(e + 1.0f);
}
DEV_INLINE f32x4 zero4() { f32x4 z; z[0]=0.f; z[1]=0.f; z[2]=0.f; z[3]=0.f; return z; }

// ---------------------------------------------------------------------------
// Weight cast + transpose: W[K][N] fp32 -> Wt[N][K] bf16 (per blockIdx.z layer)
// ---------------------------------------------------------------------------
__global__ __launch_bounds__(256) void k_cast_t(
    const float* __restrict__ W, unsigned short* __restrict__ Wt, int K, int N)
{
  __shared__ float s[64][68];
  const int tid = threadIdx.x;
  const size_t lay = (size_t)blockIdx.z * K * N;
  const int k0 = blockIdx.x * 64, n0 = blockIdx.y * 64;
  const int r = tid >> 4, c4 = (tid & 15) << 2;
  #pragma unroll
  for (int i = 0; i < 4; ++i)
    *(float4*)&s[r + i * 16][c4] =
        *(const float4*)(W + lay + (size_t)(k0 + r + i * 16) * N + n0 + c4);
  __syncthreads();
  const int n = tid & 63, kc = (tid >> 6) << 4;
  short8v v0, v1;
  #pragma unroll
  for (int j = 0; j < 8; ++j) v0[j] = (short)f2bf(s[kc + j][n]);
  #pragma unroll
  for (int j = 0; j < 8; ++j) v1[j] = (short)f2bf(s[kc + 8 + j][n]);
  unsigned short* dst = Wt + lay + (size_t)(n0 + n) * K + k0 + kc;
  *(short8v*)dst = v0;
  *(short8v*)(dst + 8) = v1;
}

// gp1w cast with coef fold: g1t[n][k] = bf16(coef[k] * gp1w[k][n])
__global__ __launch_bounds__(128) void k_cast_g1(
    const float* __restrict__ gp1w, const float* __restrict__ gstds,
    unsigned short* __restrict__ g1t)
{
  const int k = threadIdx.x;
  const int n = blockIdx.x;
  float sd = fabsf(gstds[k]) + 1e-5f;
  float coef = 0.39894268f / sd;
  g1t[n * 128 + k] = f2bf(coef * gp1w[k * 128 + n]);
}

// ---------------------------------------------------------------------------
// MFMA GEMM (R1/R6-proven reg-staged, 2 barriers/K-tile), templated tile.
// C[2048][N] = A[2048][K](bf16) @ Bt[N][K]^T + bias
// EPI: 0 bias->bf16 | 1 bias+gelu->bf16 | 2 bias+res->fp32 | 4 bias->bf16 P+Vt
// ---------------------------------------------------------------------------
template<int BM, int BN, int EPI>
__global__ __launch_bounds__(256) void k_gemm(
    const unsigned short* __restrict__ A, const unsigned short* __restrict__ Bt,
    const float* __restrict__ bias, const float* __restrict__ res,
    void* __restrict__ C, unsigned short* __restrict__ Vt, int N, int K)
{
  constexpr int MA = BM / 32;
  constexpr int NB = BN / 32;
  __shared__ __align__(16) unsigned short As[BM * 64];
  __shared__ __align__(16) unsigned short Bs[BN * 64];
  const int tid = threadIdx.x;
  const int l = tid & 63;
  const int w = tid >> 6, wr = w >> 1, wc = w & 1;
  const int row0 = blockIdx.x * BM, col0 = blockIdx.y * BN;
  const int NT = K >> 6;

  const int rA = tid >> 3;
  const int cs = (((tid & 7) * 16) ^ ((rA & 7) << 4)) >> 1;
  const unsigned short* pa = A + (size_t)(row0 + rA) * K + (tid & 7) * 8;
  const unsigned short* pb = Bt + (size_t)(col0 + rA) * K + (tid & 7) * 8;

  short8v ra[MA], rb[NB];
  #pragma unroll
  for (int i = 0; i < MA; ++i) ra[i] = *(const short8v*)(pa + (size_t)i * 32 * K);
  #pragma unroll
  for (int i = 0; i < NB; ++i) rb[i] = *(const short8v*)(pb + (size_t)i * 32 * K);

  f32x4 acc[MA][NB];
  #pragma unroll
  for (int mi = 0; mi < MA; ++mi)
    #pragma unroll
    for (int ni = 0; ni < NB; ++ni) acc[mi][ni] = zero4();

  for (int kt = 0; kt < NT; ++kt) {
    #pragma unroll
    for (int i = 0; i < MA; ++i) *(short8v*)&As[(rA + i * 32) * 64 + cs] = ra[i];
    #pragma unroll
    for (int i = 0; i < NB; ++i) *(short8v*)&Bs[(rA + i * 32) * 64 + cs] = rb[i];
    __syncthreads();
    if (kt + 1 < NT) {
      const unsigned short* qa = pa + (size_t)(kt + 1) * 64;
      const unsigned short* qb = pb + (size_t)(kt + 1) * 64;
      #pragma unroll
      for (int i = 0; i < MA; ++i) ra[i] = *(const short8v*)(qa + (size_t)i * 32 * K);
      #pragma unroll
      for (int i = 0; i < NB; ++i) rb[i] = *(const short8v*)(qb + (size_t)i * 32 * K);
    }
    #pragma unroll
    for (int kk = 0; kk < 2; ++kk) {
      short8v af[MA], bf_[NB];
      #pragma unroll
      for (int mi = 0; mi < MA; ++mi) {
        int rw = wr * (BM / 2) + mi * 16 + (l & 15);
        int kb = (kk * 64 + ((l >> 4) << 4)) ^ ((rw & 7) << 4);
        af[mi] = *(const short8v*)&As[rw * 64 + (kb >> 1)];
      }
      #pragma unroll
      for (int ni = 0; ni < NB; ++ni) {
        int rw = wc * (BN / 2) + ni * 16 + (l & 15);
        int kb = (kk * 64 + ((l >> 4) << 4)) ^ ((rw & 7) << 4);
        bf_[ni] = *(const short8v*)&Bs[rw * 64 + (kb >> 1)];
      }
      #pragma unroll
      for (int mi = 0; mi < MA; ++mi)
        #pragma unroll
        for (int ni = 0; ni < NB; ++ni)
          acc[mi][ni] = __builtin_amdgcn_mfma_f32_16x16x32_bf16(
              af[mi], bf_[ni], acc[mi][ni], 0, 0, 0);
    }
    __syncthreads();
  }

  const int cl = l & 15, rg = (l >> 4) << 2;
  #pragma unroll
  for (int mi = 0; mi < MA; ++mi) {
    #pragma unroll
    for (int ni = 0; ni < NB; ++ni) {
      const int colg = col0 + wc * (BN / 2) + ni * 16 + cl;
      const float bv = bias[colg];
      const size_t rbase = (size_t)(row0 + wr * (BM / 2) + mi * 16 + rg);
      if (EPI == 4) {
        short4v pk;
        #pragma unroll
        for (int r = 0; r < 4; ++r) {
          float v = acc[mi][ni][r] + bv;
          unsigned short bb = f2bf(v);
          ((unsigned short*)C)[(rbase + r) * N + colg] = bb;
          pk[r] = (short)bb;
        }
        const int hh = colg / 96, dd = colg - hh * 96;
        const int bb_ = (int)(rbase >> 8), tok = (int)(rbase & 255);
        *(short4v*)(Vt + ((size_t)((bb_ << 3) + hh) * 96 + dd) * 256 + tok) = pk;
      } else {
        #pragma unroll
        for (int r = 0; r < 4; ++r) {
          size_t off = (rbase + r) * N + colg;
          float v = acc[mi][ni][r] + bv;
          if (EPI == 0) ((unsigned short*)C)[off] = f2bf(v);
          if (EPI == 1) ((unsigned short*)C)[off] = f2bf(gelu_f(v));
          if (EPI == 2) ((float*)C)[off] = v + res[off];
        }
      }
    }
  }
}

// ---------------------------------------------------------------------------
// Gaussian edge features + MLP via MFMA. 512 thr = 8 waves, 128 pos/block
// (grid 4096). Params packed (mean,c2) float2 -> float4 vector LDS reads.
// (R10-measured: 143 us)
// ---------------------------------------------------------------------------
__global__ __launch_bounds__(512) void k_gauss(
    const float* __restrict__ dist, const int* __restrict__ edge,
    const float* __restrict__ gmul, const float* __restrict__ gbias,
    const float* __restrict__ gmeans, const float* __restrict__ gstds,
    const unsigned short* __restrict__ gp1wt, const float* __restrict__ gp1b,
    const float* __restrict__ gp2w, const float* __restrict__ gp2b,
    unsigned short* __restrict__ bias_out)
{
  __shared__ __align__(16) float2 mc[128];   // (mean, c2)
  __shared__ float b1s[128];
  __shared__ float b2s[8];
  __shared__ __align__(16) unsigned short w2t[16 * 136];
  __shared__ __align__(16) unsigned short t1[8][2048];  // per-wave 16x128 bf16
  const int tid = threadIdx.x, l = tid & 63, w = tid >> 6;  // w: 0..7
  const int pos0 = blockIdx.x * 128;

  if (tid < 128) {
    float sd = fabsf(gstds[tid]) + 1e-5f;
    float inv = 1.0f / sd;
    mc[tid] = make_float2(gmeans[tid], -0.72134752f * inv * inv);  // -log2e/2*inv^2
    b1s[tid] = gp1b[tid];
  }
  if (tid < 8) b2s[tid] = gp2b[tid];
  for (int i = tid; i < 2048; i += 512) {
    int hh = i & 15, k = i >> 4;
    w2t[hh * 136 + k] = (hh < 8) ? f2bf(gp2w[k * 8 + hh]) : (unsigned short)0;
  }
  __syncthreads();   // the only barrier

  const int p = pos0 + w * 16 + (l & 15);
  const int et = edge[p];
  const float y = gmul[et] * dist[p] + gbias[et];

  // phase A: gaussians straight into A-fragments; params via float4 reads
  short8v ga[4];
  #pragma unroll
  for (int ks = 0; ks < 4; ++ks) {
    const int k0 = ks * 32 + ((l >> 4) << 3);
    const float4 q0 = *(const float4*)&mc[k0];
    const float4 q1 = *(const float4*)&mc[k0 + 2];
    const float4 q2 = *(const float4*)&mc[k0 + 4];
    const float4 q3 = *(const float4*)&mc[k0 + 6];
    float d;
    d = y - q0.x; ga[ks][0] = (short)f2bf_hw(__builtin_amdgcn_exp2f(q0.y * d * d));
    d = y - q0.z; ga[ks][1] = (short)f2bf_hw(__builtin_amdgcn_exp2f(q0.w * d * d));
    d = y - q1.x; ga[ks][2] = (short)f2bf_hw(__builtin_amdgcn_exp2f(q1.y * d * d));
    d = y - q1.z; ga[ks][3] = (short)f2bf_hw(__builtin_amdgcn_exp2f(q1.w * d * d));
    d = y - q2.x; ga[ks][4] = (short)f2bf_hw(__builtin_amdgcn_exp2f(q2.y * d * d));
    d = y - q2.z; ga[ks][5] = (short)f2bf_hw(__builtin_amdgcn_exp2f(q2.w * d * d));
    d = y - q3.x; ga[ks][6] = (short)f2bf_hw(__builtin_amdgcn_exp2f(q3.y * d * d));
    d = y - q3.z; ga[ks][7] = (short)f2bf_hw(__builtin_amdgcn_exp2f(q3.w * d * d));
  }
  // phase B: t = g @ (coef-folded W1), B-frags from L2-hot g1t
  f32x4 acc[8];
  #pragma unroll
  for (int n = 0; n < 8; ++n) {
    acc[n] = zero4();
    const unsigned short* bp = gp1wt + (size_t)(n * 16 + (l & 15)) * 128 + ((l >> 4) << 3);
    #pragma unroll
    for (int ks = 0; ks < 4; ++ks)
      acc[n] = __builtin_amdgcn_mfma_f32_16x16x32_bf16(
          ga[ks], *(const short8v*)(bp + ks * 32), acc[n], 0, 0, 0);
  }
  // tanh-gelu -> per-wave t1 (windowed swizzle)
  unsigned short* tw = t1[w];
  {
    const int rb = (l >> 4) << 2;
    #pragma unroll
    for (int n = 0; n < 8; ++n) {
      int col2 = (n * 16 + (l & 15)) * 2;
      float bb = b1s[n * 16 + (l & 15)];
      #pragma unroll
      for (int r = 0; r < 4; ++r) {
        int row = rb + r;
        int swz = ((row & 3) << 4) ^ ((row >> 2) << 5);
        tw[(row * 256 + (col2 ^ swz)) >> 1] = f2bf_hw(gelu_tanh(acc[n][r] + bb));
      }
    }
  }
  // phase C: pb = t1 @ gp2w (same-wave LDS dep, no barrier)
  f32x4 o4 = zero4();
  {
    const int row = l & 15;
    const int swz = ((row & 3) << 4) ^ ((row >> 2) << 5);
    #pragma unroll
    for (int ks = 0; ks < 4; ++ks) {
      short8v af = *(const short8v*)&tw[(row * 256 + ((ks * 64 + ((l >> 4) << 4)) ^ swz)) >> 1];
      short8v bf_ = *(const short8v*)&w2t[(l & 15) * 136 + ks * 32 + ((l >> 4) << 3)];
      o4 = __builtin_amdgcn_mfma_f32_16x16x32_bf16(af, bf_, o4, 0, 0, 0);
    }
  }
  const int hh = l & 15;
  if (hh < 8) {
    int b = pos0 >> 16;
    int ij = (pos0 & 65535) + w * 16 + ((l >> 4) << 2);
    short4v ov;
    #pragma unroll
    for (int r = 0; r < 4; ++r) ov[r] = (short)f2bf(o4[r] + b2s[hh]);
    *(short4v*)(bias_out + (((size_t)((b << 3) + hh)) << 16) + ij) = ov;
  }
}

// ---------------------------------------------------------------------------
// Embedding gather + LN_emb -> x, then LN1 -> hO bf16 (fused, one kernel)
// ---------------------------------------------------------------------------
__global__ __launch_bounds__(256) void k_embed2(
    const float* __restrict__ emb, const int* __restrict__ tokens,
    const float* __restrict__ eg, const float* __restrict__ eb,
    const float* __restrict__ g1, const float* __restrict__ bp1,
    float* __restrict__ x, unsigned short* __restrict__ h)
{
  __shared__ float red[4], red2[4];
  const int t = threadIdx.x;
  const int row = blockIdx.x;
  const float* xr = emb + (size_t)tokens[row] * 768;
  float v0 = xr[t], v1 = xr[t + 256], v2 = xr[t + 512];
  float s = v0 + v1 + v2;
  #pragma unroll
  for (int o = 32; o; o >>= 1) s += __shfl_down(s, o);
  if ((t & 63) == 0) red[t >> 6] = s;
  __syncthreads();
  float mean = (red[0] + red[1] + red[2] + red[3]) * (1.0f / 768.0f);
  float d0 = v0 - mean, d1 = v1 - mean, d2 = v2 - mean;
  float q = d0 * d0 + d1 * d1 + d2 * d2;
  #pragma unroll
  for (int o = 32; o; o >>= 1) q += __shfl_down(q, o);
  if ((t & 63) == 0) red2[t >> 6] = q;
  __syncthreads();
  float rstd = rsqrtf((red2[0] + red2[1] + red2[2] + red2[3]) * (1.0f / 768.0f) + 1e-3f);
  float* outr = x + (size_t)row * 768;
  float y0 = d0 * rstd * eg[t]       + eb[t];
  float y1 = d1 * rstd * eg[t + 256] + eb[t + 256];
  float y2 = d2 * rstd * eg[t + 512] + eb[t + 512];
  outr[t] = y0; outr[t + 256] = y1; outr[t + 512] = y2;
  __syncthreads();
  s = y0 + y1 + y2;
  #pragma unroll
  for (int o = 32; o; o >>= 1) s += __shfl_down(s, o);
  if ((t & 63) == 0) red[t >> 6] = s;
  __syncthreads();
  mean = (red[0] + red[1] + red[2] + red[3]) * (1.0f / 768.0f);
  d0 = y0 - mean; d1 = y1 - mean; d2 = y2 - mean;
  q = d0 * d0 + d1 * d1 + d2 * d2;
  #pragma unroll
  for (int o = 32; o; o >>= 1) q += __shfl_down(q, o);
  if ((t & 63) == 0) red2[t >> 6] = q;
  __syncthreads();
  rstd = rsqrtf((red2[0] + red2[1] + red2[2] + red2[3]) * (1.0f / 768.0f) + 1e-3f);
  unsigned short* hr = h + (size_t)row * 768;
  hr[t]       = f2bf(d0 * rstd * g1[t]       + bp1[t]);
  hr[t + 256] = f2bf(d1 * rstd * g1[t + 256] + bp1[t + 256]);
  hr[t + 512] = f2bf(d2 * rstd * g1[t + 512] + bp1[t + 512]);
}

// LayerNorm fp32 -> bf16 h
__global__ __launch_bounds__(256) void k_ln_bf(
    const float* __restrict__ in, const float* __restrict__ g,
    const float* __restrict__ bp, unsigned short* __restrict__ out)
{
  __shared__ float red[4], red2[4];
  const int t = threadIdx.x;
  const size_t base = (size_t)blockIdx.x * 768;
  const float* xr = in + base;
  float v0 = xr[t], v1 = xr[t + 256], v2 = xr[t + 512];
  float s = v0 + v1 + v2;
  #pragma unroll
  for (int o = 32; o; o >>= 1) s += __shfl_down(s, o);
  if ((t & 63) == 0) red[t >> 6] = s;
  __syncthreads();
  float mean = (red[0] + red[1] + red[2] + red[3]) * (1.0f / 768.0f);
  float d0 = v0 - mean, d1 = v1 - mean, d2 = v2 - mean;
  float q = d0 * d0 + d1 * d1 + d2 * d2;
  #pragma unroll
  for (int o = 32; o; o >>= 1) q += __shfl_down(q, o);
  if ((t & 63) == 0) red2[t >> 6] = q;
  __syncthreads();
  float rstd = rsqrtf((red2[0] + red2[1] + red2[2] + red2[3]) * (1.0f / 768.0f) + 1e-3f);
  unsigned short* outr = out + base;
  outr[t]       = f2bf(d0 * rstd * g[t]       + bp[t]);
  outr[t + 256] = f2bf(d1 * rstd * g[t + 256] + bp[t + 256]);
  outr[t + 512] = f2bf(d2 * rstd * g[t + 512] + bp[t + 512]);
}

// ---------------------------------------------------------------------------
// Fused attention: probs = softmax(scale*Q.K^T + bias_bf16); O = probs @ V.
// 128 thr = 2 waves x 16 q-rows, grid (8,64)=512 blocks (2 blocks/CU -> TLP).
// K/V frags from L2-hot global; zero barriers. V n=0 prefetched.
// ---------------------------------------------------------------------------
__global__ __launch_bounds__(128) void k_attn(
    const unsigned short* __restrict__ P, const unsigned short* __restrict__ Vt,
    const unsigned short* __restrict__ bias, unsigned short* __restrict__ O)
{
  __shared__ __align__(16) unsigned short pl[2][4096];
  const int tid = threadIdx.x, l = tid & 63, w = tid >> 6;  // w: 0..1
  const int i0 = blockIdx.x << 5, bh = blockIdx.y, b = bh >> 3, hh = bh & 7;
  const unsigned short* Pb = P + (size_t)b * 196608 + hh * 96;

  short8v aq[3];
  const int rq = i0 + w * 16 + (l & 15);
  #pragma unroll
  for (int ks = 0; ks < 3; ++ks)
    aq[ks] = *(const short8v*)(Pb + (size_t)rq * 768 + ks * 32 + ((l >> 4) << 3));

  f32x4 acc[16];
  __builtin_amdgcn_s_setprio(1);
  #pragma unroll
  for (int n = 0; n < 16; ++n) {
    acc[n] = zero4();
    const unsigned short* kp = Pb + (size_t)(n * 16 + (l & 15)) * 768 + ((l >> 4) << 3);
    #pragma unroll
    for (int ks = 0; ks < 3; ++ks)
      acc[n] = __builtin_amdgcn_mfma_f32_16x16x32_bf16(
          aq[ks], *(const short8v*)(kp + ks * 32), acc[n], 0, 0, 0);
  }
  __builtin_amdgcn_s_setprio(0);

  // prefetch V fragments for PV n=0 (independent of softmax)
  short8v vb0[8];
  {
    const unsigned short* vbp = Vt + ((size_t)bh * 96 + (l & 15)) * 256 + ((l >> 4) << 3);
    #pragma unroll
    for (int ks = 0; ks < 8; ++ks) vb0[ks] = *(const short8v*)(vbp + ks * 32);
  }

  const float scale = 0.10206207261596577f;  // 1/sqrt(96)
  float inv[4];
  unsigned short* plw = pl[w];
  const size_t brow = ((size_t)bh * 256 + i0 + w * 16 + ((l >> 4) << 2)) * 256 + (l & 15);
  #pragma unroll
  for (int r = 0; r < 4; ++r) {
    const unsigned short* bptr = bias + brow + (size_t)r * 256;
    float m = -1e30f;
    #pragma unroll
    for (int n = 0; n < 16; ++n) {
      float v = fmaf(acc[n][r], scale, bf2f(bptr[n * 16]));
      acc[n][r] = v;
      m = fmaxf(m, v);
    }
    m = fmaxf(m, __shfl_xor(m, 1)); m = fmaxf(m, __shfl_xor(m, 2));
    m = fmaxf(m, __shfl_xor(m, 4)); m = fmaxf(m, __shfl_xor(m, 8));
    const int rowL = ((l >> 4) << 2) + r;
    const int swz = ((rowL & 3) << 4) ^ ((rowL >> 2) << 5);
    const int cb = (l & 15) << 1;
    float s = 0.f;
    #pragma unroll
    for (int n = 0; n < 16; ++n) {
      float e = __expf(acc[n][r] - m);
      s += e;
      plw[(rowL * 512 + ((cb + (n << 5)) ^ swz)) >> 1] = f2bf_hw(e);
    }
    s += __shfl_xor(s, 1); s += __shfl_xor(s, 2);
    s += __shfl_xor(s, 4); s += __shfl_xor(s, 8);
    inv[r] = 1.0f / s;
  }

  const int rowA = l & 15;
  const int swzA = ((rowA & 3) << 4) ^ ((rowA >> 2) << 5);
  short8v pa[8];
  #pragma unroll
  for (int ks = 0; ks < 8; ++ks)
    pa[ks] = *(const short8v*)&plw[(rowA * 512 + ((ks * 64 + ((l >> 4) << 4)) ^ swzA)) >> 1];

  unsigned short* Ob = O + ((size_t)b * 256 + i0 + w * 16 + ((l >> 4) << 2)) * 768
                       + hh * 96 + (l & 15);
  __builtin_amdgcn_s_setprio(1);
  #pragma unroll
  for (int n = 0; n < 6; ++n) {
    f32x4 a2 = zero4();
    const unsigned short* vb = Vt + ((size_t)bh * 96 + n * 16 + (l & 15)) * 256 + ((l >> 4) << 3);
    #pragma unroll
    for (int ks = 0; ks < 8; ++ks) {
      short8v bv = (n == 0) ? vb0[ks] : *(const short8v*)(vb + ks * 32);
      a2 = __builtin_amdgcn_mfma_f32_16x16x32_bf16(pa[ks], bv, a2, 0, 0, 0);
    }
    #pragma unroll
    for (int r = 0; r < 4; ++r)
      Ob[(size_t)r * 768 + n * 16] = f2bf(a2[r] * inv[r]);
  }
  __builtin_amdgcn_s_setprio(0);
}

// ---------------------------------------------------------------------------
// Classifier (R9-proven split): LN(row0) -> lnb; t1 = gelu(ln@w1+b1) (24 blk);
// out = t1@w2 + b2 (8 blk).
// ---------------------------------------------------------------------------
__global__ __launch_bounds__(256) void k_cls_ln(
    const float* __restrict__ x, const float* __restrict__ fg,
    const float* __restrict__ fb, float* __restrict__ lnb)
{
  __shared__ float red[4], red2[4];
  const int t = threadIdx.x;
  const int b = blockIdx.x;
  const float* xr = x + (size_t)b * 196608;
  float v0 = xr[t], v1 = xr[t + 256], v2 = xr[t + 512];
  float s = v0 + v1 + v2;
  #pragma unroll
  for (int o = 32; o; o >>= 1) s += __shfl_down(s, o);
  if ((t & 63) == 0) red[t >> 6] = s;
  __syncthreads();
  float mean = (red[0] + red[1] + red[2] + red[3]) * (1.0f / 768.0f);
  float d0 = v0 - mean, d1 = v1 - mean, d2 = v2 - mean;
  float q = d0 * d0 + d1 * d1 + d2 * d2;
  #pragma unroll
  for (int o = 32; o; o >>= 1) q += __shfl_down(q, o);
  if ((t & 63) == 0) red2[t >> 6] = q;
  __syncthreads();
  float rstd = rsqrtf((red2[0] + red2[1] + red2[2] + red2[3]) * (1.0f / 768.0f) + 1e-3f);
  float* outr = lnb + b * 768;
  outr[t]       = d0 * rstd * fg[t]       + fb[t];
  outr[t + 256] = d1 * rstd * fg[t + 256] + fb[t + 256];
  outr[t + 512] = d2 * rstd * fg[t + 512] + fb[t + 512];
}

__global__ __launch_bounds__(256) void k_cls_mm(
    const float* __restrict__ lnb, const float* __restrict__ w1,
    const float* __restrict__ b1v, float* __restrict__ t1g)
{
  __shared__ float ln[768];
  const int t = threadIdx.x;
  const int b = blockIdx.x, c0 = blockIdx.y * 256;
  #pragma unroll
  for (int i = 0; i < 3; ++i) ln[t + i * 256] = lnb[b * 768 + t + i * 256];
  __syncthreads();
  float a = b1v[c0 + t];
  for (int d = 0; d < 768; ++d)
    a = fmaf(ln[d], w1[d * 768 + c0 + t], a);
  t1g[b * 768 + c0 + t] = gelu_f(a);
}

__global__ __launch_bounds__(256) void k_cls_out(
    const float* __restrict__ t1g, const float* __restrict__ w2,
    const float* __restrict__ b2v, float* __restrict__ out)
{
  __shared__ float r2[8];
  const int t = threadIdx.x;
  const int b = blockIdx.x;
  float p0 = 0.f, p1 = 0.f;
  #pragma unroll
  for (int oo = 0; oo < 3; ++oo) {
    int d = t + oo * 256;
    float v = t1g[b * 768 + d];
    p0 = fmaf(v, w2[d * 2], p0);
    p1 = fmaf(v, w2[d * 2 + 1], p1);
  }
  #pragma unroll
  for (int o = 32; o; o >>= 1) {
    p0 += __shfl_down(p0, o);
    p1 += __shfl_down(p1, o);
  }
  if ((t & 63) == 0) { r2[t >> 6] = p0; r2[4 + (t >> 6)] = p1; }
  __syncthreads();
  if (t == 0) {
    out[b * 2]     = r2[0] + r2[1] + r2[2] + r2[3] + b2v[0];
    out[b * 2 + 1] = r2[4] + r2[5] + r2[6] + r2[7] + b2v[1];
  }
}

// ---------------------------------------------------------------------------
extern "C" void kernel_launch(void* const* d_in, const int* in_sizes, int n_in,
                              void* d_out, int out_size, void* d_ws, size_t ws_size,
                              hipStream_t stream)
{
  const float* dist    = (const float*)d_in[0];
  const float* tok_emb = (const float*)d_in[1];
  const float* gmeans  = (const float*)d_in[2];
  const float* gstds   = (const float*)d_in[3];
  const float* gmul    = (const float*)d_in[4];
  const float* gbias   = (const float*)d_in[5];
  const float* gp1w    = (const float*)d_in[6];
  const float* gp1b    = (const float*)d_in[7];
  const float* gp2w    = (const float*)d_in[8];
  const float* gp2b    = (const float*)d_in[9];
  const float* embg    = (const float*)d_in[10];
  const float* embb    = (const float*)d_in[11];
  const float* Wq      = (const float*)d_in[12];
  const float* bq      = (const float*)d_in[13];
  const float* Wo      = (const float*)d_in[14];
  const float* bo      = (const float*)d_in[15];
  const float* ln1g    = (const float*)d_in[16];
  const float* ln1b    = (const float*)d_in[17];
  const float* W1      = (const float*)d_in[18];
  const float* b1      = (const float*)d_in[19];
  const float* W2      = (const float*)d_in[20];
  const float* b2      = (const float*)d_in[21];
  const float* ln2g    = (const float*)d_in[22];
  const float* ln2b    = (const float*)d_in[23];
  const float* fing    = (const float*)d_in[24];
  const float* finb    = (const float*)d_in[25];
  const float* cw1     = (const float*)d_in[26];
  const float* cb1     = (const float*)d_in[27];
  const float* cw2     = (const float*)d_in[28];
  const float* cb2     = (const float*)d_in[29];
  const int*   tokens  = (const int*)d_in[30];
  const int*   edge    = (const int*)d_in[31];

  // workspace layout
  float* ws   = (float*)d_ws;
  float* x    = ws;                        // 1,572,864 f32
  float* lnb  = x + 1572864;               //     6,144 f32
  float* t1g  = lnb + 6144;                //     6,144 f32
  unsigned short* biasb = (unsigned short*)(t1g + 6144);  // 4,194,304 bf16
  unsigned short* hO  = biasb + 4194304;                  // 1,572,864 bf16 (h & O)
  unsigned short* P   = hO + 1572864;                     // 1,572,864 bf16
  unsigned short* Vt  = P + 1572864;                      // 1,572,864 bf16
  unsigned short* f1  = Vt + 1572864;                     // 6,291,456 bf16
  unsigned short* Wqt = f1 + 6291456;                     // 4,718,592 bf16
  unsigned short* Wot = Wqt + 4718592;                    // 4,718,592 bf16
  unsigned short* W1t = Wot + 4718592;                    // 18,874,368 bf16
  unsigned short* W2t = W1t + 18874368;                   // 18,874,368 bf16
  unsigned short* g1t = W2t + 18874368;                   // 16,384 bf16
  // total ~131 MiB

  k_cast_g1<<<128, 128, 0, stream>>>(gp1w, gstds, g1t);
  k_gauss<<<4096, 512, 0, stream>>>(dist, edge, gmul, gbias, gmeans, gstds,
                                    g1t, gp1b, gp2w, gp2b, biasb);
  k_cast_t<<<dim3(12, 12, 8), 256, 0, stream>>>(Wq, Wqt, 768, 768);
  k_cast_t<<<dim3(12, 12, 8), 256, 0, stream>>>(Wo, Wot, 768, 768);
  k_cast_t<<<dim3(12, 48, 8), 256, 0, stream>>>(W1, W1t, 768, 3072);
  k_cast_t<<<dim3(48, 12, 8), 256, 0, stream>>>(W2, W2t, 3072, 768);
  k_embed2<<<2048, 256, 0, stream>>>(tok_emb, tokens, embg, embb, ln1g, ln1b, x, hO);

  for (int l = 0; l < 8; ++l) {
    // QKV: epilogue writes P (bf16) and Vt (transposed)
    k_gemm<64, 64, 4><<<dim3(32, 12), 256, 0, stream>>>(
        hO, Wqt + (size_t)l * 589824, bq + l * 768, nullptr, P, Vt, 768, 768);
    k_attn<<<dim3(8, 64), 128, 0, stream>>>(P, Vt, biasb, hO);
    // Wo: x += Wo(O)+bo
    k_gemm<64, 64, 2><<<dim3(32, 12), 256, 0, stream>>>(
        hO, Wot + (size_t)l * 589824, bo + l * 768, x, x, nullptr, 768, 768);
    k_ln_bf<<<2048, 256, 0, stream>>>(x, ln2g + l * 768, ln2b + l * 768, hO);
    // FFN1: gelu -> f1 (bf16)
    k_gemm<128, 128, 1><<<dim3(16, 24), 256, 0, stream>>>(
        hO, W1t + (size_t)l * 2359296, b1 + l * 3072, nullptr, f1, nullptr, 3072, 768);
    // FFN2: x += FFN2(f1)+b2
    k_gemm<64, 64, 2><<<dim3(32, 12), 256, 0, stream>>>(
        f1, W2t + (size_t)l * 2359296, b2 + l * 768, x, x, nullptr, 768, 3072);
    if (l < 7)
      k_ln_bf<<<2048, 256, 0, stream>>>(x, ln1g + (l + 1) * 768,
                                        ln1b + (l + 1) * 768, hO);
  }
  k_cls_ln<<<8, 256, 0, stream>>>(x, fing, finb, lnb);
  k_cls_mm<<<dim3(8, 3), 256, 0, stream>>>(lnb, cw1, cb1, t1g);
  k_cls_out<<<8, 256, 0, stream>>>(t1g, cw2, cb2, (float*)d_out);
}

// Round 12
// 1003.106 us; speedup vs baseline: 1.0358x; 1.0125x over previous
//
#include <hip/hip_runtime.h>
#include <hip/hip_bf16.h>
#include <math.h>

// Gen3Dmol_Classify: B=8 N=256 D=768 H=8 HD=96 F=3072 K=128 L=8 V=32 E=1024 C=2
// Round 12: R11 base; k_ln_bf -> wave-per-row (no LDS/barriers, grid 512).

#define DEV_INLINE __device__ __forceinline__

typedef __attribute__((ext_vector_type(8))) short short8v;
typedef __attribute__((ext_vector_type(4))) short short4v;
typedef __attribute__((ext_vector_type(4))) float f32x4;

DEV_INLINE unsigned short f2bf(float f) {          // RNE, manual
  unsigned u = __float_as_uint(f);
  return (unsigned short)((u + 0x7fffu + ((u >> 16) & 1u)) >> 16);
}
DEV_INLINE unsigned short f2bf_hw(float f) {
  __hip_bfloat16 h = __float2bfloat16(f);
  unsigned short u; __builtin_memcpy(&u, &h, 2); return u;
}
DEV_INLINE float bf2f(unsigned short u) {
  return __uint_as_float(((unsigned)u) << 16);
}
DEV_INLINE float gelu_f(float v) {                 // exact (residual-path users)
  return 0.5f * v * (1.0f + erff(v * 0.70710678118654752f));
}
DEV_INLINE float gelu_tanh(float x) {              // fast approx (gauss bias path)
  float x2 = x * x;
  float t  = x * fmaf(0.044715f, x2, 1.0f);
  float a  = fminf(2.3022082f * t, 252.0f);
  float e  = __builtin_amdgcn_exp2f(a);
  return x * e * __frcp_rn(e + 1.0f);
}
DEV_INLINE f32x4 zero4() { f32x4 z; z[0]=0.f; z[1]=0.f; z[2]=0.f; z[3]=0.f; return z; }

// ---------------------------------------------------------------------------
// Weight cast + transpose: W[K][N] fp32 -> Wt[N][K] bf16 (per blockIdx.z layer)
// ---------------------------------------------------------------------------
__global__ __launch_bounds__(256) void k_cast_t(
    const float* __restrict__ W, unsigned short* __restrict__ Wt, int K, int N)
{
  __shared__ float s[64][68];
  const int tid = threadIdx.x;
  const size_t lay = (size_t)blockIdx.z * K * N;
  const int k0 = blockIdx.x * 64, n0 = blockIdx.y * 64;
  const int r = tid >> 4, c4 = (tid & 15) << 2;
  #pragma unroll
  for (int i = 0; i < 4; ++i)
    *(float4*)&s[r + i * 16][c4] =
        *(const float4*)(W + lay + (size_t)(k0 + r + i * 16) * N + n0 + c4);
  __syncthreads();
  const int n = tid & 63, kc = (tid >> 6) << 4;
  short8v v0, v1;
  #pragma unroll
  for (int j = 0; j < 8; ++j) v0[j] = (short)f2bf(s[kc + j][n]);
  #pragma unroll
  for (int j = 0; j < 8; ++j) v1[j] = (short)f2bf(s[kc + 8 + j][n]);
  unsigned short* dst = Wt + lay + (size_t)(n0 + n) * K + k0 + kc;
  *(short8v*)dst = v0;
  *(short8v*)(dst + 8) = v1;
}

// gp1w cast with coef fold: g1t[n][k] = bf16(coef[k] * gp1w[k][n])
__global__ __launch_bounds__(128) void k_cast_g1(
    const float* __restrict__ gp1w, const float* __restrict__ gstds,
    unsigned short* __restrict__ g1t)
{
  const int k = threadIdx.x;
  const int n = blockIdx.x;
  float sd = fabsf(gstds[k]) + 1e-5f;
  float coef = 0.39894268f / sd;
  g1t[n * 128 + k] = f2bf(coef * gp1w[k * 128 + n]);
}

// ---------------------------------------------------------------------------
// MFMA GEMM (R1/R6-proven reg-staged, 2 barriers/K-tile), templated tile.
// C[2048][N] = A[2048][K](bf16) @ Bt[N][K]^T + bias
// EPI: 0 bias->bf16 | 1 bias+gelu->bf16 | 2 bias+res->fp32 | 4 bias->bf16 P+Vt
// ---------------------------------------------------------------------------
template<int BM, int BN, int EPI>
__global__ __launch_bounds__(256) void k_gemm(
    const unsigned short* __restrict__ A, const unsigned short* __restrict__ Bt,
    const float* __restrict__ bias, const float* __restrict__ res,
    void* __restrict__ C, unsigned short* __restrict__ Vt, int N, int K)
{
  constexpr int MA = BM / 32;
  constexpr int NB = BN / 32;
  __shared__ __align__(16) unsigned short As[BM * 64];
  __shared__ __align__(16) unsigned short Bs[BN * 64];
  const int tid = threadIdx.x;
  const int l = tid & 63;
  const int w = tid >> 6, wr = w >> 1, wc = w & 1;
  const int row0 = blockIdx.x * BM, col0 = blockIdx.y * BN;
  const int NT = K >> 6;

  const int rA = tid >> 3;
  const int cs = (((tid & 7) * 16) ^ ((rA & 7) << 4)) >> 1;
  const unsigned short* pa = A + (size_t)(row0 + rA) * K + (tid & 7) * 8;
  const unsigned short* pb = Bt + (size_t)(col0 + rA) * K + (tid & 7) * 8;

  short8v ra[MA], rb[NB];
  #pragma unroll
  for (int i = 0; i < MA; ++i) ra[i] = *(const short8v*)(pa + (size_t)i * 32 * K);
  #pragma unroll
  for (int i = 0; i < NB; ++i) rb[i] = *(const short8v*)(pb + (size_t)i * 32 * K);

  f32x4 acc[MA][NB];
  #pragma unroll
  for (int mi = 0; mi < MA; ++mi)
    #pragma unroll
    for (int ni = 0; ni < NB; ++ni) acc[mi][ni] = zero4();

  for (int kt = 0; kt < NT; ++kt) {
    #pragma unroll
    for (int i = 0; i < MA; ++i) *(short8v*)&As[(rA + i * 32) * 64 + cs] = ra[i];
    #pragma unroll
    for (int i = 0; i < NB; ++i) *(short8v*)&Bs[(rA + i * 32) * 64 + cs] = rb[i];
    __syncthreads();
    if (kt + 1 < NT) {
      const unsigned short* qa = pa + (size_t)(kt + 1) * 64;
      const unsigned short* qb = pb + (size_t)(kt + 1) * 64;
      #pragma unroll
      for (int i = 0; i < MA; ++i) ra[i] = *(const short8v*)(qa + (size_t)i * 32 * K);
      #pragma unroll
      for (int i = 0; i < NB; ++i) rb[i] = *(const short8v*)(qb + (size_t)i * 32 * K);
    }
    #pragma unroll
    for (int kk = 0; kk < 2; ++kk) {
      short8v af[MA], bf_[NB];
      #pragma unroll
      for (int mi = 0; mi < MA; ++mi) {
        int rw = wr * (BM / 2) + mi * 16 + (l & 15);
        int kb = (kk * 64 + ((l >> 4) << 4)) ^ ((rw & 7) << 4);
        af[mi] = *(const short8v*)&As[rw * 64 + (kb >> 1)];
      }
      #pragma unroll
      for (int ni = 0; ni < NB; ++ni) {
        int rw = wc * (BN / 2) + ni * 16 + (l & 15);
        int kb = (kk * 64 + ((l >> 4) << 4)) ^ ((rw & 7) << 4);
        bf_[ni] = *(const short8v*)&Bs[rw * 64 + (kb >> 1)];
      }
      #pragma unroll
      for (int mi = 0; mi < MA; ++mi)
        #pragma unroll
        for (int ni = 0; ni < NB; ++ni)
          acc[mi][ni] = __builtin_amdgcn_mfma_f32_16x16x32_bf16(
              af[mi], bf_[ni], acc[mi][ni], 0, 0, 0);
    }
    __syncthreads();
  }

  const int cl = l & 15, rg = (l >> 4) << 2;
  #pragma unroll
  for (int mi = 0; mi < MA; ++mi) {
    #pragma unroll
    for (int ni = 0; ni < NB; ++ni) {
      const int colg = col0 + wc * (BN / 2) + ni * 16 + cl;
      const float bv = bias[colg];
      const size_t rbase = (size_t)(row0 + wr * (BM / 2) + mi * 16 + rg);
      if (EPI == 4) {
        short4v pk;
        #pragma unroll
        for (int r = 0; r < 4; ++r) {
          float v = acc[mi][ni][r] + bv;
          unsigned short bb = f2bf(v);
          ((unsigned short*)C)[(rbase + r) * N + colg] = bb;
          pk[r] = (short)bb;
        }
        const int hh = colg / 96, dd = colg - hh * 96;
        const int bb_ = (int)(rbase >> 8), tok = (int)(rbase & 255);
        *(short4v*)(Vt + ((size_t)((bb_ << 3) + hh) * 96 + dd) * 256 + tok) = pk;
      } else {
        #pragma unroll
        for (int r = 0; r < 4; ++r) {
          size_t off = (rbase + r) * N + colg;
          float v = acc[mi][ni][r] + bv;
          if (EPI == 0) ((unsigned short*)C)[off] = f2bf(v);
          if (EPI == 1) ((unsigned short*)C)[off] = f2bf(gelu_f(v));
          if (EPI == 2) ((float*)C)[off] = v + res[off];
        }
      }
    }
  }
}

// ---------------------------------------------------------------------------
// Gaussian edge features + MLP via MFMA. 512 thr = 8 waves, 128 pos/block
// (grid 4096). Params packed (mean,c2) float2 -> float4 vector LDS reads.
// (R10/R11-measured: ~142 us)
// ---------------------------------------------------------------------------
__global__ __launch_bounds__(512) void k_gauss(
    const float* __restrict__ dist, const int* __restrict__ edge,
    const float* __restrict__ gmul, const float* __restrict__ gbias,
    const float* __restrict__ gmeans, const float* __restrict__ gstds,
    const unsigned short* __restrict__ gp1wt, const float* __restrict__ gp1b,
    const float* __restrict__ gp2w, const float* __restrict__ gp2b,
    unsigned short* __restrict__ bias_out)
{
  __shared__ __align__(16) float2 mc[128];   // (mean, c2)
  __shared__ float b1s[128];
  __shared__ float b2s[8];
  __shared__ __align__(16) unsigned short w2t[16 * 136];
  __shared__ __align__(16) unsigned short t1[8][2048];  // per-wave 16x128 bf16
  const int tid = threadIdx.x, l = tid & 63, w = tid >> 6;  // w: 0..7
  const int pos0 = blockIdx.x * 128;

  if (tid < 128) {
    float sd = fabsf(gstds[tid]) + 1e-5f;
    float inv = 1.0f / sd;
    mc[tid] = make_float2(gmeans[tid], -0.72134752f * inv * inv);  // -log2e/2*inv^2
    b1s[tid] = gp1b[tid];
  }
  if (tid < 8) b2s[tid] = gp2b[tid];
  for (int i = tid; i < 2048; i += 512) {
    int hh = i & 15, k = i >> 4;
    w2t[hh * 136 + k] = (hh < 8) ? f2bf(gp2w[k * 8 + hh]) : (unsigned short)0;
  }
  __syncthreads();   // the only barrier

  const int p = pos0 + w * 16 + (l & 15);
  const int et = edge[p];
  const float y = gmul[et] * dist[p] + gbias[et];

  // phase A: gaussians straight into A-fragments; params via float4 reads
  short8v ga[4];
  #pragma unroll
  for (int ks = 0; ks < 4; ++ks) {
    const int k0 = ks * 32 + ((l >> 4) << 3);
    const float4 q0 = *(const float4*)&mc[k0];
    const float4 q1 = *(const float4*)&mc[k0 + 2];
    const float4 q2 = *(const float4*)&mc[k0 + 4];
    const float4 q3 = *(const float4*)&mc[k0 + 6];
    float d;
    d = y - q0.x; ga[ks][0] = (short)f2bf_hw(__builtin_amdgcn_exp2f(q0.y * d * d));
    d = y - q0.z; ga[ks][1] = (short)f2bf_hw(__builtin_amdgcn_exp2f(q0.w * d * d));
    d = y - q1.x; ga[ks][2] = (short)f2bf_hw(__builtin_amdgcn_exp2f(q1.y * d * d));
    d = y - q1.z; ga[ks][3] = (short)f2bf_hw(__builtin_amdgcn_exp2f(q1.w * d * d));
    d = y - q2.x; ga[ks][4] = (short)f2bf_hw(__builtin_amdgcn_exp2f(q2.y * d * d));
    d = y - q2.z; ga[ks][5] = (short)f2bf_hw(__builtin_amdgcn_exp2f(q2.w * d * d));
    d = y - q3.x; ga[ks][6] = (short)f2bf_hw(__builtin_amdgcn_exp2f(q3.y * d * d));
    d = y - q3.z; ga[ks][7] = (short)f2bf_hw(__builtin_amdgcn_exp2f(q3.w * d * d));
  }
  // phase B: t = g @ (coef-folded W1), B-frags from L2-hot g1t
  f32x4 acc[8];
  #pragma unroll
  for (int n = 0; n < 8; ++n) {
    acc[n] = zero4();
    const unsigned short* bp = gp1wt + (size_t)(n * 16 + (l & 15)) * 128 + ((l >> 4) << 3);
    #pragma unroll
    for (int ks = 0; ks < 4; ++ks)
      acc[n] = __builtin_amdgcn_mfma_f32_16x16x32_bf16(
          ga[ks], *(const short8v*)(bp + ks * 32), acc[n], 0, 0, 0);
  }
  // tanh-gelu -> per-wave t1 (windowed swizzle)
  unsigned short* tw = t1[w];
  {
    const int rb = (l >> 4) << 2;
    #pragma unroll
    for (int n = 0; n < 8; ++n) {
      int col2 = (n * 16 + (l & 15)) * 2;
      float bb = b1s[n * 16 + (l & 15)];
      #pragma unroll
      for (int r = 0; r < 4; ++r) {
        int row = rb + r;
        int swz = ((row & 3) << 4) ^ ((row >> 2) << 5);
        tw[(row * 256 + (col2 ^ swz)) >> 1] = f2bf_hw(gelu_tanh(acc[n][r] + bb));
      }
    }
  }
  // phase C: pb = t1 @ gp2w (same-wave LDS dep, no barrier)
  f32x4 o4 = zero4();
  {
    const int row = l & 15;
    const int swz = ((row & 3) << 4) ^ ((row >> 2) << 5);
    #pragma unroll
    for (int ks = 0; ks < 4; ++ks) {
      short8v af = *(const short8v*)&tw[(row * 256 + ((ks * 64 + ((l >> 4) << 4)) ^ swz)) >> 1];
      short8v bf_ = *(const short8v*)&w2t[(l & 15) * 136 + ks * 32 + ((l >> 4) << 3)];
      o4 = __builtin_amdgcn_mfma_f32_16x16x32_bf16(af, bf_, o4, 0, 0, 0);
    }
  }
  const int hh = l & 15;
  if (hh < 8) {
    int b = pos0 >> 16;
    int ij = (pos0 & 65535) + w * 16 + ((l >> 4) << 2);
    short4v ov;
    #pragma unroll
    for (int r = 0; r < 4; ++r) ov[r] = (short)f2bf(o4[r] + b2s[hh]);
    *(short4v*)(bias_out + (((size_t)((b << 3) + hh)) << 16) + ij) = ov;
  }
}

// ---------------------------------------------------------------------------
// Embedding gather + LN_emb -> x, then LN1 -> hO bf16 (fused, one kernel)
// ---------------------------------------------------------------------------
__global__ __launch_bounds__(256) void k_embed2(
    const float* __restrict__ emb, const int* __restrict__ tokens,
    const float* __restrict__ eg, const float* __restrict__ eb,
    const float* __restrict__ g1, const float* __restrict__ bp1,
    float* __restrict__ x, unsigned short* __restrict__ h)
{
  __shared__ float red[4], red2[4];
  const int t = threadIdx.x;
  const int row = blockIdx.x;
  const float* xr = emb + (size_t)tokens[row] * 768;
  float v0 = xr[t], v1 = xr[t + 256], v2 = xr[t + 512];
  float s = v0 + v1 + v2;
  #pragma unroll
  for (int o = 32; o; o >>= 1) s += __shfl_down(s, o);
  if ((t & 63) == 0) red[t >> 6] = s;
  __syncthreads();
  float mean = (red[0] + red[1] + red[2] + red[3]) * (1.0f / 768.0f);
  float d0 = v0 - mean, d1 = v1 - mean, d2 = v2 - mean;
  float q = d0 * d0 + d1 * d1 + d2 * d2;
  #pragma unroll
  for (int o = 32; o; o >>= 1) q += __shfl_down(q, o);
  if ((t & 63) == 0) red2[t >> 6] = q;
  __syncthreads();
  float rstd = rsqrtf((red2[0] + red2[1] + red2[2] + red2[3]) * (1.0f / 768.0f) + 1e-3f);
  float* outr = x + (size_t)row * 768;
  float y0 = d0 * rstd * eg[t]       + eb[t];
  float y1 = d1 * rstd * eg[t + 256] + eb[t + 256];
  float y2 = d2 * rstd * eg[t + 512] + eb[t + 512];
  outr[t] = y0; outr[t + 256] = y1; outr[t + 512] = y2;
  __syncthreads();
  s = y0 + y1 + y2;
  #pragma unroll
  for (int o = 32; o; o >>= 1) s += __shfl_down(s, o);
  if ((t & 63) == 0) red[t >> 6] = s;
  __syncthreads();
  mean = (red[0] + red[1] + red[2] + red[3]) * (1.0f / 768.0f);
  d0 = y0 - mean; d1 = y1 - mean; d2 = y2 - mean;
  q = d0 * d0 + d1 * d1 + d2 * d2;
  #pragma unroll
  for (int o = 32; o; o >>= 1) q += __shfl_down(q, o);
  if ((t & 63) == 0) red2[t >> 6] = q;
  __syncthreads();
  rstd = rsqrtf((red2[0] + red2[1] + red2[2] + red2[3]) * (1.0f / 768.0f) + 1e-3f);
  unsigned short* hr = h + (size_t)row * 768;
  hr[t]       = f2bf(d0 * rstd * g1[t]       + bp1[t]);
  hr[t + 256] = f2bf(d1 * rstd * g1[t + 256] + bp1[t + 256]);
  hr[t + 512] = f2bf(d2 * rstd * g1[t + 512] + bp1[t + 512]);
}

// ---------------------------------------------------------------------------
// LayerNorm fp32 -> bf16, one WAVE per row (no LDS, no barriers).
// 4 rows per 256-thr block, grid 512. Lane covers 12 contiguous elements.
// ---------------------------------------------------------------------------
__global__ __launch_bounds__(256) void k_ln_bf(
    const float* __restrict__ in, const float* __restrict__ g,
    const float* __restrict__ bp, unsigned short* __restrict__ out)
{
  const int l = threadIdx.x & 63;
  const int wv = threadIdx.x >> 6;
  const size_t row = (size_t)blockIdx.x * 4 + wv;
  const int c0 = l * 12;
  const float* xr = in + row * 768 + c0;
  float4 a = *(const float4*)xr;
  float4 b = *(const float4*)(xr + 4);
  float4 c = *(const float4*)(xr + 8);
  float s = (a.x + a.y) + (a.z + a.w) + (b.x + b.y) + (b.z + b.w)
          + (c.x + c.y) + (c.z + c.w);
  #pragma unroll
  for (int o = 32; o; o >>= 1) s += __shfl_xor(s, o);
  const float mean = s * (1.0f / 768.0f);
  float v[12] = {a.x, a.y, a.z, a.w, b.x, b.y, b.z, b.w, c.x, c.y, c.z, c.w};
  float q = 0.f;
  #pragma unroll
  for (int i = 0; i < 12; ++i) {
    v[i] -= mean;
    q = fmaf(v[i], v[i], q);
  }
  #pragma unroll
  for (int o = 32; o; o >>= 1) q += __shfl_xor(q, o);
  const float rstd = rsqrtf(q * (1.0f / 768.0f) + 1e-3f);
  float4 g0 = *(const float4*)(g + c0);
  float4 g1 = *(const float4*)(g + c0 + 4);
  float4 g2 = *(const float4*)(g + c0 + 8);
  float4 b0 = *(const float4*)(bp + c0);
  float4 b1v = *(const float4*)(bp + c0 + 4);
  float4 b2v = *(const float4*)(bp + c0 + 8);
  const float gr[12] = {g0.x, g0.y, g0.z, g0.w, g1.x, g1.y, g1.z, g1.w,
                        g2.x, g2.y, g2.z, g2.w};
  const float br[12] = {b0.x, b0.y, b0.z, b0.w, b1v.x, b1v.y, b1v.z, b1v.w,
                        b2v.x, b2v.y, b2v.z, b2v.w};
  short4v o0, o1, o2;
  #pragma unroll
  for (int i = 0; i < 4; ++i) o0[i] = (short)f2bf(fmaf(v[i] * rstd, gr[i], br[i]));
  #pragma unroll
  for (int i = 0; i < 4; ++i) o1[i] = (short)f2bf(fmaf(v[4 + i] * rstd, gr[4 + i], br[4 + i]));
  #pragma unroll
  for (int i = 0; i < 4; ++i) o2[i] = (short)f2bf(fmaf(v[8 + i] * rstd, gr[8 + i], br[8 + i]));
  unsigned short* outr = out + row * 768 + c0;
  *(short4v*)outr = o0;
  *(short4v*)(outr + 4) = o1;
  *(short4v*)(outr + 8) = o2;
}

// ---------------------------------------------------------------------------
// Fused attention: probs = softmax(scale*Q.K^T + bias_bf16); O = probs @ V.
// 128 thr = 2 waves x 16 q-rows, grid (8,64)=512 blocks (2 blocks/CU -> TLP).
// K/V frags from L2-hot global; zero barriers. V n=0 prefetched.
// ---------------------------------------------------------------------------
__global__ __launch_bounds__(128) void k_attn(
    const unsigned short* __restrict__ P, const unsigned short* __restrict__ Vt,
    const unsigned short* __restrict__ bias, unsigned short* __restrict__ O)
{
  __shared__ __align__(16) unsigned short pl[2][4096];
  const int tid = threadIdx.x, l = tid & 63, w = tid >> 6;  // w: 0..1
  const int i0 = blockIdx.x << 5, bh = blockIdx.y, b = bh >> 3, hh = bh & 7;
  const unsigned short* Pb = P + (size_t)b * 196608 + hh * 96;

  short8v aq[3];
  const int rq = i0 + w * 16 + (l & 15);
  #pragma unroll
  for (int ks = 0; ks < 3; ++ks)
    aq[ks] = *(const short8v*)(Pb + (size_t)rq * 768 + ks * 32 + ((l >> 4) << 3));

  f32x4 acc[16];
  __builtin_amdgcn_s_setprio(1);
  #pragma unroll
  for (int n = 0; n < 16; ++n) {
    acc[n] = zero4();
    const unsigned short* kp = Pb + (size_t)(n * 16 + (l & 15)) * 768 + ((l >> 4) << 3);
    #pragma unroll
    for (int ks = 0; ks < 3; ++ks)
      acc[n] = __builtin_amdgcn_mfma_f32_16x16x32_bf16(
          aq[ks], *(const short8v*)(kp + ks * 32), acc[n], 0, 0, 0);
  }
  __builtin_amdgcn_s_setprio(0);

  // prefetch V fragments for PV n=0 (independent of softmax)
  short8v vb0[8];
  {
    const unsigned short* vbp = Vt + ((size_t)bh * 96 + (l & 15)) * 256 + ((l >> 4) << 3);
    #pragma unroll
    for (int ks = 0; ks < 8; ++ks) vb0[ks] = *(const short8v*)(vbp + ks * 32);
  }

  const float scale = 0.10206207261596577f;  // 1/sqrt(96)
  float inv[4];
  unsigned short* plw = pl[w];
  const size_t brow = ((size_t)bh * 256 + i0 + w * 16 + ((l >> 4) << 2)) * 256 + (l & 15);
  #pragma unroll
  for (int r = 0; r < 4; ++r) {
    const unsigned short* bptr = bias + brow + (size_t)r * 256;
    float m = -1e30f;
    #pragma unroll
    for (int n = 0; n < 16; ++n) {
      float v = fmaf(acc[n][r], scale, bf2f(bptr[n * 16]));
      acc[n][r] = v;
      m = fmaxf(m, v);
    }
    m = fmaxf(m, __shfl_xor(m, 1)); m = fmaxf(m, __shfl_xor(m, 2));
    m = fmaxf(m, __shfl_xor(m, 4)); m = fmaxf(m, __shfl_xor(m, 8));
    const int rowL = ((l >> 4) << 2) + r;
    const int swz = ((rowL & 3) << 4) ^ ((rowL >> 2) << 5);
    const int cb = (l & 15) << 1;
    float s = 0.f;
    #pragma unroll
    for (int n = 0; n < 16; ++n) {
      float e = __expf(acc[n][r] - m);
      s += e;
      plw[(rowL * 512 + ((cb + (n << 5)) ^ swz)) >> 1] = f2bf_hw(e);
    }
    s += __shfl_xor(s, 1); s += __shfl_xor(s, 2);
    s += __shfl_xor(s, 4); s += __shfl_xor(s, 8);
    inv[r] = 1.0f / s;
  }

  const int rowA = l & 15;
  const int swzA = ((rowA & 3) << 4) ^ ((rowA >> 2) << 5);
  short8v pa[8];
  #pragma unroll
  for (int ks = 0; ks < 8; ++ks)
    pa[ks] = *(const short8v*)&plw[(rowA * 512 + ((ks * 64 + ((l >> 4) << 4)) ^ swzA)) >> 1];

  unsigned short* Ob = O + ((size_t)b * 256 + i0 + w * 16 + ((l >> 4) << 2)) * 768
                       + hh * 96 + (l & 15);
  __builtin_amdgcn_s_setprio(1);
  #pragma unroll
  for (int n = 0; n < 6; ++n) {
    f32x4 a2 = zero4();
    const unsigned short* vb = Vt + ((size_t)bh * 96 + n * 16 + (l & 15)) * 256 + ((l >> 4) << 3);
    #pragma unroll
    for (int ks = 0; ks < 8; ++ks) {
      short8v bv = (n == 0) ? vb0[ks] : *(const short8v*)(vb + ks * 32);
      a2 = __builtin_amdgcn_mfma_f32_16x16x32_bf16(pa[ks], bv, a2, 0, 0, 0);
    }
    #pragma unroll
    for (int r = 0; r < 4; ++r)
      Ob[(size_t)r * 768 + n * 16] = f2bf(a2[r] * inv[r]);
  }
  __builtin_amdgcn_s_setprio(0);
}

// ---------------------------------------------------------------------------
// Classifier (R9/R11-proven split): LN(row0) -> lnb; t1 = gelu(ln@w1+b1);
// out = t1@w2 + b2.
// ---------------------------------------------------------------------------
__global__ __launch_bounds__(256) void k_cls_ln(
    const float* __restrict__ x, const float* __restrict__ fg,
    const float* __restrict__ fb, float* __restrict__ lnb)
{
  __shared__ float red[4], red2[4];
  const int t = threadIdx.x;
  const int b = blockIdx.x;
  const float* xr = x + (size_t)b * 196608;
  float v0 = xr[t], v1 = xr[t + 256], v2 = xr[t + 512];
  float s = v0 + v1 + v2;
  #pragma unroll
  for (int o = 32; o; o >>= 1) s += __shfl_down(s, o);
  if ((t & 63) == 0) red[t >> 6] = s;
  __syncthreads();
  float mean = (red[0] + red[1] + red[2] + red[3]) * (1.0f / 768.0f);
  float d0 = v0 - mean, d1 = v1 - mean, d2 = v2 - mean;
  float q = d0 * d0 + d1 * d1 + d2 * d2;
  #pragma unroll
  for (int o = 32; o; o >>= 1) q += __shfl_down(q, o);
  if ((t & 63) == 0) red2[t >> 6] = q;
  __syncthreads();
  float rstd = rsqrtf((red2[0] + red2[1] + red2[2] + red2[3]) * (1.0f / 768.0f) + 1e-3f);
  float* outr = lnb + b * 768;
  outr[t]       = d0 * rstd * fg[t]       + fb[t];
  outr[t + 256] = d1 * rstd * fg[t + 256] + fb[t + 256];
  outr[t + 512] = d2 * rstd * fg[t + 512] + fb[t + 512];
}

__global__ __launch_bounds__(256) void k_cls_mm(
    const float* __restrict__ lnb, const float* __restrict__ w1,
    const float* __restrict__ b1v, float* __restrict__ t1g)
{
  __shared__ float ln[768];
  const int t = threadIdx.x;
  const int b = blockIdx.x, c0 = blockIdx.y * 256;
  #pragma unroll
  for (int i = 0; i < 3; ++i) ln[t + i * 256] = lnb[b * 768 + t + i * 256];
  __syncthreads();
  float a = b1v[c0 + t];
  for (int d = 0; d < 768; ++d)
    a = fmaf(ln[d], w1[d * 768 + c0 + t], a);
  t1g[b * 768 + c0 + t] = gelu_f(a);
}

__global__ __launch_bounds__(256) void k_cls_out(
    const float* __restrict__ t1g, const float* __restrict__ w2,
    const float* __restrict__ b2v, float* __restrict__ out)
{
  __shared__ float r2[8];
  const int t = threadIdx.x;
  const int b = blockIdx.x;
  float p0 = 0.f, p1 = 0.f;
  #pragma unroll
  for (int oo = 0; oo < 3; ++oo) {
    int d = t + oo * 256;
    float v = t1g[b * 768 + d];
    p0 = fmaf(v, w2[d * 2], p0);
    p1 = fmaf(v, w2[d * 2 + 1], p1);
  }
  #pragma unroll
  for (int o = 32; o; o >>= 1) {
    p0 += __shfl_down(p0, o);
    p1 += __shfl_down(p1, o);
  }
  if ((t & 63) == 0) { r2[t >> 6] = p0; r2[4 + (t >> 6)] = p1; }
  __syncthreads();
  if (t == 0) {
    out[b * 2]     = r2[0] + r2[1] + r2[2] + r2[3] + b2v[0];
    out[b * 2 + 1] = r2[4] + r2[5] + r2[6] + r2[7] + b2v[1];
  }
}

// ---------------------------------------------------------------------------
extern "C" void kernel_launch(void* const* d_in, const int* in_sizes, int n_in,
                              void* d_out, int out_size, void* d_ws, size_t ws_size,
                              hipStream_t stream)
{
  const float* dist    = (const float*)d_in[0];
  const float* tok_emb = (const float*)d_in[1];
  const float* gmeans  = (const float*)d_in[2];
  const float* gstds   = (const float*)d_in[3];
  const float* gmul    = (const float*)d_in[4];
  const float* gbias   = (const float*)d_in[5];
  const float* gp1w    = (const float*)d_in[6];
  const float* gp1b    = (const float*)d_in[7];
  const float* gp2w    = (const float*)d_in[8];
  const float* gp2b    = (const float*)d_in[9];
  const float* embg    = (const float*)d_in[10];
  const float* embb    = (const float*)d_in[11];
  const float* Wq      = (const float*)d_in[12];
  const float* bq      = (const float*)d_in[13];
  const float* Wo      = (const float*)d_in[14];
  const float* bo      = (const float*)d_in[15];
  const float* ln1g    = (const float*)d_in[16];
  const float* ln1b    = (const float*)d_in[17];
  const float* W1      = (const float*)d_in[18];
  const float* b1      = (const float*)d_in[19];
  const float* W2      = (const float*)d_in[20];
  const float* b2      = (const float*)d_in[21];
  const float* ln2g    = (const float*)d_in[22];
  const float* ln2b    = (const float*)d_in[23];
  const float* fing    = (const float*)d_in[24];
  const float* finb    = (const float*)d_in[25];
  const float* cw1     = (const float*)d_in[26];
  const float* cb1     = (const float*)d_in[27];
  const float* cw2     = (const float*)d_in[28];
  const float* cb2     = (const float*)d_in[29];
  const int*   tokens  = (const int*)d_in[30];
  const int*   edge    = (const int*)d_in[31];

  // workspace layout
  float* ws   = (float*)d_ws;
  float* x    = ws;                        // 1,572,864 f32
  float* lnb  = x + 1572864;               //     6,144 f32
  float* t1g  = lnb + 6144;                //     6,144 f32
  unsigned short* biasb = (unsigned short*)(t1g + 6144);  // 4,194,304 bf16
  unsigned short* hO  = biasb + 4194304;                  // 1,572,864 bf16 (h & O)
  unsigned short* P   = hO + 1572864;                     // 1,572,864 bf16
  unsigned short* Vt  = P + 1572864;                      // 1,572,864 bf16
  unsigned short* f1  = Vt + 1572864;                     // 6,291,456 bf16
  unsigned short* Wqt = f1 + 6291456;                     // 4,718,592 bf16
  unsigned short* Wot = Wqt + 4718592;                    // 4,718,592 bf16
  unsigned short* W1t = Wot + 4718592;                    // 18,874,368 bf16
  unsigned short* W2t = W1t + 18874368;                   // 18,874,368 bf16
  unsigned short* g1t = W2t + 18874368;                   // 16,384 bf16
  // total ~131 MiB

  k_cast_g1<<<128, 128, 0, stream>>>(gp1w, gstds, g1t);
  k_gauss<<<4096, 512, 0, stream>>>(dist, edge, gmul, gbias, gmeans, gstds,
                                    g1t, gp1b, gp2w, gp2b, biasb);
  k_cast_t<<<dim3(12, 12, 8), 256, 0, stream>>>(Wq, Wqt, 768, 768);
  k_cast_t<<<dim3(12, 12, 8), 256, 0, stream>>>(Wo, Wot, 768, 768);
  k_cast_t<<<dim3(12, 48, 8), 256, 0, stream>>>(W1, W1t, 768, 3072);
  k_cast_t<<<dim3(48, 12, 8), 256, 0, stream>>>(W2, W2t, 3072, 768);
  k_embed2<<<2048, 256, 0, stream>>>(tok_emb, tokens, embg, embb, ln1g, ln1b, x, hO);

  for (int l = 0; l < 8; ++l) {
    // QKV: epilogue writes P (bf16) and Vt (transposed)
    k_gemm<64, 64, 4><<<dim3(32, 12), 256, 0, stream>>>(
        hO, Wqt + (size_t)l * 589824, bq + l * 768, nullptr, P, Vt, 768, 768);
    k_attn<<<dim3(8, 64), 128, 0, stream>>>(P, Vt, biasb, hO);
    // Wo: x += Wo(O)+bo
    k_gemm<64, 64, 2><<<dim3(32, 12), 256, 0, stream>>>(
        hO, Wot + (size_t)l * 589824, bo + l * 768, x, x, nullptr, 768, 768);
    k_ln_bf<<<512, 256, 0, stream>>>(x, ln2g + l * 768, ln2b + l * 768, hO);
    // FFN1: gelu -> f1 (bf16)
    k_gemm<128, 128, 1><<<dim3(16, 24), 256, 0, stream>>>(
        hO, W1t + (size_t)l * 2359296, b1 + l * 3072, nullptr, f1, nullptr, 3072, 768);
    // FFN2: x += FFN2(f1)+b2
    k_gemm<64, 64, 2><<<dim3(32, 12), 256, 0, stream>>>(
        f1, W2t + (size_t)l * 2359296, b2 + l * 768, x, x, nullptr, 768, 3072);
    if (l < 7)
      k_ln_bf<<<512, 256, 0, stream>>>(x, ln1g + (l + 1) * 768,
                                       ln1b + (l + 1) * 768, hO);
  }
  k_cls_ln<<<8, 256, 0, stream>>>(x, fing, finb, lnb);
  k_cls_mm<<<dim3(8, 3), 256, 0, stream>>>(lnb, cw1, cb1, t1g);
  k_cls_out<<<8, 256, 0, stream>>>(t1g, cw2, cb2, (float*)d_out);
}